// Round 7
// baseline (629.804 us; speedup 1.0000x reference)
//
#include <hip/hip_runtime.h>

typedef unsigned int uint;
typedef unsigned short ushort;
typedef unsigned char uchar;
typedef __attribute__((ext_vector_type(8))) short bf16x8;
typedef __attribute__((ext_vector_type(8))) ushort ushort8;
typedef __attribute__((ext_vector_type(4))) float f32x4;

// ---------- helpers ----------
__device__ __forceinline__ float silu_fast(float t) {
  return t * __builtin_amdgcn_rcpf(1.f + __expf(-t));
}
__device__ __forceinline__ float bf2f(ushort u) {
  union { uint i; float f; } v; v.i = ((uint)u) << 16; return v.f;
}
__device__ __forceinline__ float bf2f_lo(uint u) {
  union { uint i; float f; } v; v.i = u << 16; return v.f;
}
__device__ __forceinline__ float bf2f_hi(uint u) {
  union { uint i; float f; } v; v.i = u & 0xffff0000u; return v.f;
}
__device__ __forceinline__ ushort f2bf(float f) {
  union { float f; uint i; } v; v.f = f;
  uint r = (v.i + 0x7fffu + ((v.i >> 16) & 1u)) >> 16;
  return (ushort)r;
}
__device__ __forceinline__ uint cvtpk_bf(float a, float b) {
  uint r; asm("v_cvt_pk_bf16_f32 %0, %1, %2" : "=v"(r) : "v"(a), "v"(b)); return r;
}
// fp8 e4m3 (OCP) encode, RNE, sat-to-448
__device__ __forceinline__ uchar f2e4m3(float f) {
  uint u = __float_as_uint(f);
  uint s = (u >> 24) & 0x80u;
  uint m = u & 0x7fffffffu;
  if (m >= 0x43f00000u) return (uchar)(s | 0x7e);
  if (m >= 0x3c800000u) {
    uint r = m + 0x7ffffu + ((m >> 20) & 1u);
    uint e = (r >> 23) - 120u;
    if (e > 15u) return (uchar)(s | 0x7e);
    return (uchar)(s | (e << 3) | ((r >> 20) & 7u));
  }
  float az = __uint_as_float(m);
  uint k = (uint)__float2int_rn(az * 512.f);
  return (uchar)(s | k);
}
__device__ __forceinline__ uint pk4_e4m3(float4 v) {
  return (uint)f2e4m3(v.x) | ((uint)f2e4m3(v.y) << 8)
       | ((uint)f2e4m3(v.z) << 16) | ((uint)f2e4m3(v.w) << 24);
}
__device__ __forceinline__ float e4m3f(uint b) {
  uint u = ((b & 0x80u) << 24) | ((b & 0x7fu) << 20);
  return __uint_as_float(u) * 0x1p+120f;
}

// ---------- mega prep: c1 | wnode | W1g | W2T | wcomb | cw2bf | count ----------
__global__ __launch_bounds__(256) void mega_prep(
    const float* __restrict__ x, const int* __restrict__ ei,
    const float* __restrict__ wq, const float* __restrict__ wk, const float* __restrict__ wv,
    const float* __restrict__ bq, const float* __restrict__ bk, const float* __restrict__ bv,
    const float* __restrict__ ew1, const float* __restrict__ eb1,
    const float* __restrict__ pw1, const float* __restrict__ pb1,
    const float* __restrict__ ew2, const float* __restrict__ eww,
    const float* __restrict__ eb2, const float* __restrict__ ewb,
    const float* __restrict__ pw2, const float* __restrict__ pb2,
    const float* __restrict__ wo, const float* __restrict__ cw3,
    const float* __restrict__ bo, const float* __restrict__ cb3,
    const float* __restrict__ cw1, const float* __restrict__ cb1,
    const float* __restrict__ cw2,
    ushort* __restrict__ c1,
    ushort* __restrict__ wnode, float* __restrict__ bqkv,
    short* __restrict__ W1g,
    short* __restrict__ W2T, float* __restrict__ biasC,
    ushort* __restrict__ wcomb, float* __restrict__ bcomb,
    ushort* __restrict__ cw2bf, int* __restrict__ cnt,
    int n, int E,
    int o1, int o2, int o3, int o4, int o5, int o6)
{
  int b = blockIdx.x, tid = threadIdx.x;
  if (b < o1) {                       // c1 = silu(x@cw1^T+cb1) bf16
    int idx = b * 256 + tid;
    if (idx < n * 256) {
      int node = idx >> 8, j = idx & 255;
      float t = fmaf(x[node * 3 + 2], cw1[j * 3 + 2],
                fmaf(x[node * 3 + 1], cw1[j * 3 + 1],
                fmaf(x[node * 3 + 0], cw1[j * 3 + 0], cb1[j])));
      c1[idx] = f2bf(silu_fast(t));
    }
  } else if (b < o2) {                // wnode [2048][128] bf16 + bqkv
    int idx = (b - o1) * 256 + tid;
    if (idx < 2048 * 128) {
      int j = idx >> 7, k = idx & 127;
      float v;
      if (j < 512)       v = wq[j * 128 + k];
      else if (j < 1024) v = wk[(j - 512) * 128 + k];
      else if (j < 1536) v = wv[(j - 1024) * 128 + k];
      else if (j < 1792) v = ew1[(j - 1536) * 263 + k];
      else               v = ew1[(j - 1792) * 263 + 128 + k];
      wnode[idx] = f2bf(v);
      if (idx < 1536)
        bqkv[idx] = (idx < 512) ? bq[idx] : (idx < 1024) ? bk[idx - 512] : bv[idx - 1024];
    }
  } else if (b < o3) {                // W1g [512 n][32 k]: geom+bias projection
    int idx = (b - o2) * 256 + tid;
    if (idx < 512 * 32) {
      int nn = idx >> 5, k = idx & 31;
      float v = 0.f;
      if (nn < 256) {
        if (k == 0)      v = eb1[nn];
        else if (k < 8)  v = ew1[nn * 263 + 256 + (k - 1)];   // rd, xr(3), xc(3)
      } else {
        int p = nn - 256;
        if (k == 0)           v = pb1[p];
        else if (k >= 2 && k < 8) v = pw1[p * 6 + (k - 2)];   // xr(3), xc(3)
      }
      W1g[idx] = (short)f2bf(v);
    }
  } else if (b < o4) {                // W2T [16][512] + biasC
    int idx = (b - o3) * 256 + tid;
    if (idx < 16 * 512) {
      int hh = idx >> 9, k = idx & 511;
      float v = 0.f;
      if (hh < 8) {
        if (k < 256) {
          float s = 0.f;
          for (int j = 0; j < 256; ++j) s += eww[hh * 256 + j] * ew2[j * 256 + k];
          v = s;
        } else v = pw2[hh * 256 + (k - 256)];
      }
      W2T[idx] = (short)f2bf(v);
      if (idx < 16) {
        float bb = 0.f;
        if (idx < 8) {
          float s = 0.f;
          for (int j = 0; j < 256; ++j) s += eww[idx * 256 + j] * eb2[j];
          bb = s + ewb[idx] + pb2[idx];
        }
        biasC[idx] = bb;
      }
    }
  } else if (b < o5) {                // wcomb [128][768] + bcomb
    int idx = (b - o4) * 256 + tid;
    if (idx < 128 * 768) {
      int j = idx / 768, k = idx % 768;
      float v = (k < 512) ? wo[j * 512 + k] : cw3[j * 256 + (k - 512)];
      wcomb[idx] = f2bf(v);
      if (idx < 128) bcomb[idx] = bo[idx] + cb3[idx];
    }
  } else if (b < o6) {                // cw2 bf16
    int idx = (b - o5) * 256 + tid;
    if (idx < 256 * 256) cw2bf[idx] = f2bf(cw2[idx]);
  } else {                            // count (CSR degree)
    int e = (b - o6) * 256 + tid;
    if (e < E) atomicAdd(&cnt[ei[e]], 1);
  }
}

// ---------- node projections via swapped MFMA + LDS-coalesced stores ----------
__global__ __launch_bounds__(256) void nodeproj_kernel(
    const float* __restrict__ h,        // [n][128] f32
    const ushort* __restrict__ wnode,   // [2048][128]
    const float* __restrict__ bqkv,     // [1536]
    ushort* __restrict__ q_t, uchar* __restrict__ k8, ushort* __restrict__ v_t,
    ushort* __restrict__ P1t, ushort* __restrict__ P2t,
    int n)
{
  __shared__ float oS[64 * 68];         // 17,408 B
  int tid = threadIdx.x;
  int lane = tid & 63, w = tid >> 6;
  int l15 = lane & 15, l4 = lane >> 4;
  int m0 = blockIdx.x * 64;
  int jb0 = blockIdx.y * 8;
  int mrow = m0 + w * 16 + l15;
  int mr = (mrow < n) ? mrow : (n - 1);

  bf16x8 hf[4];
#pragma unroll
  for (int ks = 0; ks < 4; ++ks) {
    const float* hp = h + (size_t)mr * 128 + ks * 32 + l4 * 8;
    float4 a0 = *(const float4*)hp;
    float4 a1 = *(const float4*)(hp + 4);
    uint4 pk;
    pk.x = cvtpk_bf(a0.x, a0.y); pk.y = cvtpk_bf(a0.z, a0.w);
    pk.z = cvtpk_bf(a1.x, a1.y); pk.w = cvtpk_bf(a1.z, a1.w);
    union { uint4 u; bf16x8 b; } cv; cv.u = pk;
    hf[ks] = cv.b;
  }

  int row = tid >> 2, cs = (tid & 3) * 16;   // writer mapping
  int gr = m0 + row;

  for (int jb = jb0; jb < jb0 + 8; ++jb) {
    f32x4 acc[4];
#pragma unroll
    for (int nf = 0; nf < 4; ++nf) acc[nf] = (f32x4){0.f, 0.f, 0.f, 0.f};
#pragma unroll
    for (int nf = 0; nf < 4; ++nf)
#pragma unroll
      for (int ks = 0; ks < 4; ++ks) {
        bf16x8 wf = *(const bf16x8*)(wnode + (size_t)(jb * 64 + nf * 16 + l15) * 128 + ks * 32 + l4 * 8);
        acc[nf] = __builtin_amdgcn_mfma_f32_16x16x32_bf16(wf, hf[ks], acc[nf], 0, 0, 0);
      }
    __syncthreads();   // previous jb's readers done
    // stage: oS[node_local][col_local]; lane's 4 acc elems are col-contiguous
#pragma unroll
    for (int nf = 0; nf < 4; ++nf)
      *(f32x4*)(oS + (w * 16 + l15) * 68 + nf * 16 + l4 * 4) = acc[nf];
    __syncthreads();
    // coalesced writers: 4 threads per row, 16 cols each
    if (gr < n) {
      float4 o0 = *(const float4*)(oS + row * 68 + cs);
      float4 o1 = *(const float4*)(oS + row * 68 + cs + 4);
      float4 o2 = *(const float4*)(oS + row * 68 + cs + 8);
      float4 o3 = *(const float4*)(oS + row * 68 + cs + 12);
      int gc = jb * 64 + cs;
      if (jb < 24) {
        float4 b0 = *(const float4*)(bqkv + gc);
        float4 b1 = *(const float4*)(bqkv + gc + 4);
        float4 b2 = *(const float4*)(bqkv + gc + 8);
        float4 b3 = *(const float4*)(bqkv + gc + 12);
        o0.x += b0.x; o0.y += b0.y; o0.z += b0.z; o0.w += b0.w;
        o1.x += b1.x; o1.y += b1.y; o1.z += b1.z; o1.w += b1.w;
        o2.x += b2.x; o2.y += b2.y; o2.z += b2.z; o2.w += b2.w;
        o3.x += b3.x; o3.y += b3.y; o3.z += b3.z; o3.w += b3.w;
        if (jb < 8) {
          uint4 s0 = {cvtpk_bf(o0.x,o0.y), cvtpk_bf(o0.z,o0.w), cvtpk_bf(o1.x,o1.y), cvtpk_bf(o1.z,o1.w)};
          uint4 s1 = {cvtpk_bf(o2.x,o2.y), cvtpk_bf(o2.z,o2.w), cvtpk_bf(o3.x,o3.y), cvtpk_bf(o3.z,o3.w)};
          *(uint4*)(q_t + (size_t)gr * 512 + gc) = s0;
          *(uint4*)(q_t + (size_t)gr * 512 + gc + 8) = s1;
        } else if (jb < 16) {
          uint4 st = {pk4_e4m3(o0), pk4_e4m3(o1), pk4_e4m3(o2), pk4_e4m3(o3)};
          *(uint4*)(k8 + (size_t)gr * 512 + (gc - 512)) = st;
        } else {
          uint4 s0 = {cvtpk_bf(o0.x,o0.y), cvtpk_bf(o0.z,o0.w), cvtpk_bf(o1.x,o1.y), cvtpk_bf(o1.z,o1.w)};
          uint4 s1 = {cvtpk_bf(o2.x,o2.y), cvtpk_bf(o2.z,o2.w), cvtpk_bf(o3.x,o3.y), cvtpk_bf(o3.z,o3.w)};
          *(uint4*)(v_t + (size_t)gr * 512 + (gc - 1024)) = s0;
          *(uint4*)(v_t + (size_t)gr * 512 + (gc - 1024) + 8) = s1;
        }
      } else {
        int pc = (jb & 3) * 64 + cs;
        uint4 s0 = {cvtpk_bf(o0.x,o0.y), cvtpk_bf(o0.z,o0.w), cvtpk_bf(o1.x,o1.y), cvtpk_bf(o1.z,o1.w)};
        uint4 s1 = {cvtpk_bf(o2.x,o2.y), cvtpk_bf(o2.z,o2.w), cvtpk_bf(o3.x,o3.y), cvtpk_bf(o3.z,o3.w)};
        ushort* P = (jb < 28) ? P1t : P2t;
        *(uint4*)(P + (size_t)gr * 256 + pc) = s0;
        *(uint4*)(P + (size_t)gr * 256 + pc + 8) = s1;
      }
    }
  }
}

// ---------- CSR scan + fill ----------
__global__ __launch_bounds__(1024) void scan_kernel(int* __restrict__ cnt,
                                                    int* __restrict__ offs, int n) {
  __shared__ int part[1024];
  int t = threadIdx.x;
  int chunk = (n + 1023) >> 10;
  int s = t * chunk, e = min(s + chunk, n);
  int sum = 0;
  for (int i = s; i < e; ++i) sum += cnt[i];
  part[t] = sum;
  __syncthreads();
  for (int off = 1; off < 1024; off <<= 1) {
    int v = (t >= off) ? part[t - off] : 0;
    __syncthreads();
    part[t] += v;
    __syncthreads();
  }
  int run = (t == 0) ? 0 : part[t - 1];
  for (int i = s; i < e; ++i) {
    int c = cnt[i];
    offs[i] = run;
    cnt[i] = run;
    run += c;
  }
  if (t == 1023) offs[n] = run;
}

// pairs[slot] = (col, row | (masked ? 0x80000000 : 0))
__global__ __launch_bounds__(256) void fill_kernel(const int* __restrict__ ei,
                                                   const int* __restrict__ mask,
                                                   int* __restrict__ cursor,
                                                   int2* __restrict__ pairs, int E) {
  int e = blockIdx.x * 256 + threadIdx.x;
  if (e < E) {
    int r = ei[e];
    int p = atomicAdd(&cursor[r], 1);
    int rm = r | (mask[e] ? 0 : (int)0x80000000u);
    pairs[p] = make_int2(ei[E + e], rm);
  }
}

// ---------- edge MLP v3: factorized, CSR-ordered ----------
#define EB 64
#define GS 40       // geom stride (shorts)
#define TS 72       // t1 stride (shorts)

__global__ __launch_bounds__(256) void edge_mfma3_kernel(
    const float* __restrict__ x,
    const int2* __restrict__ pairs, int E,
    const short* __restrict__ W1g,      // [512][32]
    const short* __restrict__ W2T, const float* __restrict__ biasC,
    const ushort* __restrict__ P1t, const ushort* __restrict__ P2t,
    float* __restrict__ scores)
{
  __shared__ short geomL[EB * GS];      // 5 KB
  __shared__ int2 rcL[EB];              // 0.5 KB
  __shared__ short T1[4 * EB * TS];     // 36,864 B
  float* slab = (float*)T1;             // overlay after layer2

  int tid = threadIdx.x;
  int lane = tid & 63, w = tid >> 6;
  int l15 = lane & 15, l4 = lane >> 4;
  int eb0 = blockIdx.x * EB;

  if (tid < EB) {
    int i = min(eb0 + tid, E - 1);
    int2 pr = pairs[i];
    rcL[tid] = pr;
    int c = pr.x, r = pr.y & 0x7fffffff;
    float xr0 = x[r*3], xr1 = x[r*3+1], xr2 = x[r*3+2];
    float xc0 = x[c*3], xc1 = x[c*3+1], xc2 = x[c*3+2];
    float d0 = xr0-xc0, d1 = xr1-xc1, d2 = xr2-xc2;
    bf16x8 g;
    g[0] = (short)0x3F80;               // 1.0 (bias input)
    g[1] = (short)f2bf(d0*d0 + d1*d1 + d2*d2);
    g[2] = (short)f2bf(xr0); g[3] = (short)f2bf(xr1); g[4] = (short)f2bf(xr2);
    g[5] = (short)f2bf(xc0); g[6] = (short)f2bf(xc1); g[7] = (short)f2bf(xc2);
    bf16x8 z = {0,0,0,0,0,0,0,0};
    *(bf16x8*)(geomL + tid * GS) = g;
    *(bf16x8*)(geomL + tid * GS + 8) = z;
    *(bf16x8*)(geomL + tid * GS + 16) = z;
    *(bf16x8*)(geomL + tid * GS + 24) = z;
    *(bf16x8*)(geomL + tid * GS + 32) = z;
  }
  __syncthreads();

  int rr[4], cc[4];
  bf16x8 bE[4];
#pragma unroll
  for (int ef = 0; ef < 4; ++ef) {
    int2 pr = rcL[ef * 16 + l15];
    cc[ef] = pr.x; rr[ef] = pr.y & 0x7fffffff;
    bE[ef] = *(const bf16x8*)(geomL + (ef * 16 + l15) * GS + l4 * 8);
  }

  f32x4 sacc[4];
#pragma unroll
  for (int ef = 0; ef < 4; ++ef) sacc[ef] = (f32x4){0.f, 0.f, 0.f, 0.f};

  short* t1w = T1 + w * (EB * TS);

#pragma unroll
  for (int cch = 0; cch < 2; ++cch) {
    const int n0 = cch ? (256 + w * 64) : (w * 64);
    f32x4 acc[4][4];
#pragma unroll
    for (int mf = 0; mf < 4; ++mf) {
      bf16x8 aW = *(const bf16x8*)(W1g + (size_t)(n0 + mf * 16 + l15) * 32 + l4 * 8);
#pragma unroll
      for (int ef = 0; ef < 4; ++ef)
        acc[mf][ef] = __builtin_amdgcn_mfma_f32_16x16x32_bf16(
            aW, bE[ef], (f32x4){0.f, 0.f, 0.f, 0.f}, 0, 0, 0);
    }
    if (cch == 0) {
#pragma unroll
      for (int mf = 0; mf < 4; ++mf) {
        int colb = n0 + mf * 16 + l4 * 4;
        uint2 g1[4], g2[4];
#pragma unroll
        for (int ef = 0; ef < 4; ++ef) {
          g1[ef] = *(const uint2*)(P1t + (size_t)rr[ef] * 256 + colb);
          g2[ef] = *(const uint2*)(P2t + (size_t)cc[ef] * 256 + colb);
        }
#pragma unroll
        for (int ef = 0; ef < 4; ++ef) {
          f32x4 a = acc[mf][ef];
          a[0] += bf2f_lo(g1[ef].x) + bf2f_lo(g2[ef].x);
          a[1] += bf2f_hi(g1[ef].x) + bf2f_hi(g2[ef].x);
          a[2] += bf2f_lo(g1[ef].y) + bf2f_lo(g2[ef].y);
          a[3] += bf2f_hi(g1[ef].y) + bf2f_hi(g2[ef].y);
          acc[mf][ef] = a;
        }
      }
    }
#pragma unroll
    for (int mf = 0; mf < 4; ++mf) {
      int nl = mf * 16 + l4 * 4;
#pragma unroll
      for (int ef = 0; ef < 4; ++ef) {
        int e = ef * 16 + l15;
        f32x4 v = acc[mf][ef];
        float s0 = silu_fast(v[0]);
        float s1 = silu_fast(v[1]);
        float s2 = silu_fast(v[2]);
        float s3 = silu_fast(v[3]);
        uint2 pk;
        pk.x = cvtpk_bf(s0, s1);
        pk.y = cvtpk_bf(s2, s3);
        *(uint2*)(t1w + e * TS + nl) = pk;
      }
    }
#pragma unroll
    for (int ks2 = 0; ks2 < 2; ++ks2) {
      bf16x8 bW2 = *(const bf16x8*)(W2T + (size_t)l15 * 512 + n0 + ks2 * 32 + l4 * 8);
#pragma unroll
      for (int ef = 0; ef < 4; ++ef) {
        bf16x8 aT = *(const bf16x8*)(t1w + (ef * 16 + l15) * TS + ks2 * 32 + l4 * 8);
        sacc[ef] = __builtin_amdgcn_mfma_f32_16x16x32_bf16(aT, bW2, sacc[ef], 0, 0, 0);
      }
    }
  }
  __syncthreads();
#pragma unroll
  for (int ef = 0; ef < 4; ++ef)
#pragma unroll
    for (int i = 0; i < 4; ++i)
      slab[(w * EB + ef * 16 + l4 * 4 + i) * 16 + l15] = sacc[ef][i];
  __syncthreads();
  for (int t = tid; t < EB * 8; t += 256) {
    int e = t >> 3, hh = t & 7;
    float s = biasC[hh]
            + slab[(0 * EB + e) * 16 + hh] + slab[(1 * EB + e) * 16 + hh]
            + slab[(2 * EB + e) * 16 + hh] + slab[(3 * EB + e) * 16 + hh];
    if (rcL[e].y < 0) s = -1e9f;
    if (eb0 + e < E) scores[(size_t)(eb0 + e) * 8 + hh] = s;
  }
}

// ---------- fused QK + softmax + aggregation ----------
__global__ __launch_bounds__(256) void attn_fused_kernel(
    const int* __restrict__ offs,
    const int2* __restrict__ pairs,
    const float* __restrict__ scores,
    const ushort* __restrict__ q_t,
    const uchar* __restrict__ k8,
    const ushort* __restrict__ v_t,
    ushort* __restrict__ agg, int n)
{
  int node = blockIdx.x * 4 + (threadIdx.x >> 6);
  if (node >= n) return;
  int lane = threadIdx.x & 63;
  int start = offs[node], end = offs[node + 1];

  bf16x8 qv = *(const bf16x8*)(q_t + (size_t)node * 512 + lane * 8);
  float qf[8];
#pragma unroll
  for (int j = 0; j < 8; ++j) qf[j] = bf2f((ushort)qv[j]);

  float m = -3.0e38f, ssum = 0.f;
  float acc[8];
#pragma unroll
  for (int j = 0; j < 8; ++j) acc[j] = 0.f;

  if (start < end) {
    int col = pairs[start].x;
    uint2 kw = *(const uint2*)(k8 + (size_t)col * 512 + lane * 8);
    bf16x8 vv = *(const bf16x8*)(v_t + (size_t)col * 512 + lane * 8);
    float sml = scores[(size_t)start * 8 + (lane >> 3)];

    for (int i = start; i < end; ++i) {
      uint2 kwc = kw; bf16x8 vvc = vv; float smlc = sml;
      int inx = (i + 1 < end) ? (i + 1) : i;
      col = pairs[inx].x;
      kw = *(const uint2*)(k8 + (size_t)col * 512 + lane * 8);
      vv = *(const bf16x8*)(v_t + (size_t)col * 512 + lane * 8);
      sml = scores[(size_t)inx * 8 + (lane >> 3)];

      float dot = 0.f;
#pragma unroll
      for (int j = 0; j < 4; ++j)
        dot = fmaf(qf[j], e4m3f((kwc.x >> (8 * j)) & 0xffu), dot);
#pragma unroll
      for (int j = 0; j < 4; ++j)
        dot = fmaf(qf[4 + j], e4m3f((kwc.y >> (8 * j)) & 0xffu), dot);
      dot += __shfl_xor(dot, 1);
      dot += __shfl_xor(dot, 2);
      dot += __shfl_xor(dot, 4);
      float s = (smlc < -5e8f) ? -1e9f : fmaf(dot, 0.125f, smlc);
      float nm = fmaxf(m, s);
      float cs = __expf(m - nm);
      float e  = __expf(s - nm);
      ssum = fmaf(ssum, cs, e);
#pragma unroll
      for (int j = 0; j < 8; ++j)
        acc[j] = fmaf(acc[j], cs, e * bf2f((ushort)vvc[j]));
      m = nm;
    }
  }
  float inv = __builtin_amdgcn_rcpf(ssum + 1e-8f);
  ushort8 ov;
#pragma unroll
  for (int j = 0; j < 8; ++j) ov[j] = f2bf(acc[j] * inv);
  *(ushort8*)(agg + (size_t)node * 512 + lane * 8) = ov;
}

// ---------- coord layer 2 via MFMA: c2 = silu(c1 @ cw2^T + cb2) bf16 ----------
__global__ __launch_bounds__(256) void c2_mfma_kernel(const ushort* __restrict__ c1,
                                                      const ushort* __restrict__ cw2bf,
                                                      const float* __restrict__ cb2,
                                                      ushort* __restrict__ c2, int n) {
  __shared__ float oS[64 * 68];
  int tid = threadIdx.x;
  int lane = tid & 63, w = tid >> 6;
  int l15 = lane & 15, l4 = lane >> 4;
  int m0 = blockIdx.x * 64;
  int n0 = blockIdx.y * 64 + w * 16;

  f32x4 acc[4];
#pragma unroll
  for (int mf = 0; mf < 4; ++mf) acc[mf] = (f32x4){0.f, 0.f, 0.f, 0.f};
#pragma unroll
  for (int ks = 0; ks < 8; ++ks) {
    bf16x8 bW = *(const bf16x8*)(cw2bf + (size_t)(n0 + l15) * 256 + ks * 32 + l4 * 8);
#pragma unroll
    for (int mf = 0; mf < 4; ++mf) {
      int gr = m0 + mf * 16 + l15; if (gr >= n) gr = n - 1;
      bf16x8 aH = *(const bf16x8*)(c1 + (size_t)gr * 256 + ks * 32 + l4 * 8);
      acc[mf] = __builtin_amdgcn_mfma_f32_16x16x32_bf16(aH, bW, acc[mf], 0, 0, 0);
    }
  }
#pragma unroll
  for (int mf = 0; mf < 4; ++mf)
#pragma unroll
    for (int i = 0; i < 4; ++i)
      oS[(mf * 16 + l4 * 4 + i) * 68 + w * 16 + l15] = acc[mf][i];
  __syncthreads();
  {
    int row = tid >> 2, cs = (tid & 3) * 16;
    int gr = m0 + row;
    if (gr < n) {
      int gc = blockIdx.y * 64 + cs;
      ushort8 o0, o1;
#pragma unroll
      for (int j = 0; j < 8; ++j) o0[j] = f2bf(silu_fast(oS[row * 68 + cs + j] + cb2[gc + j]));
#pragma unroll
      for (int j = 0; j < 8; ++j) o1[j] = f2bf(silu_fast(oS[row * 68 + cs + 8 + j] + cb2[gc + 8 + j]));
      *(ushort8*)(c2 + (size_t)gr * 256 + gc) = o0;
      *(ushort8*)(c2 + (size_t)gr * 256 + gc + 8) = o1;
    }
  }
}

// ---------- final fused out GEMM: out[n][128] = [agg|c2] @ wcomb^T + bcomb ----------
__global__ __launch_bounds__(256) void final_mfma_kernel(const ushort* __restrict__ agg,
                                                         const ushort* __restrict__ c2,
                                                         const ushort* __restrict__ wcomb,
                                                         const float* __restrict__ bcomb,
                                                         float* __restrict__ out, int n) {
  __shared__ float oS[64 * 68];
  int tid = threadIdx.x;
  int lane = tid & 63, w = tid >> 6;
  int l15 = lane & 15, l4 = lane >> 4;
  int m0 = blockIdx.x * 64;
  int jb = blockIdx.y;
  int n0 = jb * 64 + w * 16;

  f32x4 acc[4];
#pragma unroll
  for (int mf = 0; mf < 4; ++mf) acc[mf] = (f32x4){0.f, 0.f, 0.f, 0.f};
#pragma unroll
  for (int ks = 0; ks < 24; ++ks) {
    bf16x8 bW = *(const bf16x8*)(wcomb + (size_t)(n0 + l15) * 768 + ks * 32 + l4 * 8);
#pragma unroll
    for (int mf = 0; mf < 4; ++mf) {
      int gr = m0 + mf * 16 + l15; if (gr >= n) gr = n - 1;
      const ushort* ap = (ks < 16) ? (agg + (size_t)gr * 512 + ks * 32)
                                   : (c2 + (size_t)gr * 256 + (ks - 16) * 32);
      bf16x8 aH = *(const bf16x8*)(ap + l4 * 8);
      acc[mf] = __builtin_amdgcn_mfma_f32_16x16x32_bf16(aH, bW, acc[mf], 0, 0, 0);
    }
  }
#pragma unroll
  for (int mf = 0; mf < 4; ++mf)
#pragma unroll
    for (int i = 0; i < 4; ++i)
      oS[(mf * 16 + l4 * 4 + i) * 68 + w * 16 + l15] = acc[mf][i];
  __syncthreads();
  {
    int row = tid >> 2, cs = (tid & 3) * 16;
    int gr = m0 + row;
    if (gr < n) {
      int gc = jb * 64 + cs;
#pragma unroll
      for (int g = 0; g < 4; ++g) {
        float4 o;
        o.x = oS[row * 68 + cs + g * 4 + 0] + bcomb[gc + g * 4 + 0];
        o.y = oS[row * 68 + cs + g * 4 + 1] + bcomb[gc + g * 4 + 1];
        o.z = oS[row * 68 + cs + g * 4 + 2] + bcomb[gc + g * 4 + 2];
        o.w = oS[row * 68 + cs + g * 4 + 3] + bcomb[gc + g * 4 + 3];
        *(float4*)(out + (size_t)gr * 128 + gc + g * 4) = o;
      }
    }
  }
}

// ---------- launch ----------
extern "C" void kernel_launch(void* const* d_in, const int* in_sizes, int n_in,
                              void* d_out, int out_size, void* d_ws, size_t ws_size,
                              hipStream_t stream) {
  const float* h   = (const float*)d_in[0];
  const float* x   = (const float*)d_in[1];
  const int*   ei  = (const int*)d_in[2];
  const int*   mask= (const int*)d_in[3];
  const float* wq  = (const float*)d_in[4];
  const float* bq  = (const float*)d_in[5];
  const float* wk  = (const float*)d_in[6];
  const float* bk  = (const float*)d_in[7];
  const float* wv  = (const float*)d_in[8];
  const float* bv  = (const float*)d_in[9];
  const float* wo  = (const float*)d_in[10];
  const float* bo  = (const float*)d_in[11];
  const float* pw1 = (const float*)d_in[12];
  const float* pb1 = (const float*)d_in[13];
  const float* pw2 = (const float*)d_in[14];
  const float* pb2 = (const float*)d_in[15];
  const float* ew1 = (const float*)d_in[16];
  const float* eb1 = (const float*)d_in[17];
  const float* ew2 = (const float*)d_in[18];
  const float* eb2 = (const float*)d_in[19];
  const float* eww = (const float*)d_in[20];
  const float* ewb = (const float*)d_in[21];
  const float* cw1 = (const float*)d_in[22];
  const float* cb1 = (const float*)d_in[23];
  const float* cw2 = (const float*)d_in[24];
  const float* cb2 = (const float*)d_in[25];
  const float* cw3 = (const float*)d_in[26];
  const float* cb3 = (const float*)d_in[27];

  int n = in_sizes[0] / 128;
  int E = in_sizes[3];

  char* wptr = (char*)d_ws;
  auto alloc = [&](size_t bytes) {
    char* p = wptr;
    wptr += (bytes + 255) & ~(size_t)255;
    return p;
  };
  ushort* q_t   = (ushort*)alloc((size_t)n * 512 * 2);   // also reused as agg
  uchar*  k8    = (uchar*)alloc((size_t)n * 512);
  ushort* v_t   = (ushort*)alloc((size_t)n * 512 * 2);
  ushort* P1t   = (ushort*)alloc((size_t)n * 256 * 2);
  ushort* P2t   = (ushort*)alloc((size_t)n * 256 * 2);
  float* scores = (float*)alloc((size_t)E * 8 * 4);
  ushort* c1    = (ushort*)alloc((size_t)n * 256 * 2);
  ushort* c2    = (ushort*)alloc((size_t)n * 256 * 2);
  ushort* wnode = (ushort*)alloc((size_t)2048 * 128 * 2);
  float* bqkv   = (float*)alloc((size_t)1536 * 4);
  short* W1g    = (short*)alloc((size_t)512 * 32 * 2);
  short* W2T    = (short*)alloc((size_t)16 * 512 * 2);
  float* biasC  = (float*)alloc((size_t)16 * 4);
  ushort* wcomb = (ushort*)alloc((size_t)128 * 768 * 2);
  float* bcomb  = (float*)alloc((size_t)128 * 4);
  ushort* cw2bf = (ushort*)alloc((size_t)256 * 256 * 2);
  int* offs     = (int*)alloc((size_t)(n + 1) * 4);
  int* cursor   = (int*)alloc((size_t)n * 4);
  int2* pairs   = (int2*)alloc((size_t)E * 8);
  ushort* agg   = q_t;    // overlay: attn reads q[node] before writing agg[node]

  hipMemsetAsync(cursor, 0, (size_t)n * 4, stream);

  // mega-prep segment boundaries
  int b_c1  = (n * 256 + 255) / 256;
  int b_wn  = (2048 * 128) / 256;
  int b_w1  = (512 * 32 + 255) / 256;
  int b_w2  = (16 * 512 + 255) / 256;
  int b_wc  = (128 * 768 + 255) / 256;
  int b_cw  = (256 * 256 + 255) / 256;
  int b_cnt = (E + 255) / 256;
  int o1 = b_c1, o2 = o1 + b_wn, o3 = o2 + b_w1, o4 = o3 + b_w2;
  int o5 = o4 + b_wc, o6 = o5 + b_cw;
  int total_blocks = o6 + b_cnt;

  mega_prep<<<dim3(total_blocks), 256, 0, stream>>>(
      x, ei, wq, wk, wv, bq, bk, bv, ew1, eb1, pw1, pb1, ew2, eww, eb2, ewb,
      pw2, pb2, wo, cw3, bo, cb3, cw1, cb1, cw2,
      c1, wnode, bqkv, W1g, W2T, biasC, wcomb, bcomb, cw2bf, cursor,
      n, E, o1, o2, o3, o4, o5, o6);

  scan_kernel<<<dim3(1), 1024, 0, stream>>>(cursor, offs, n);
  fill_kernel<<<dim3((E + 255) / 256), 256, 0, stream>>>(ei, mask, cursor, pairs, E);

  nodeproj_kernel<<<dim3((n + 63) / 64, 4), 256, 0, stream>>>(
      h, wnode, bqkv, q_t, k8, v_t, P1t, P2t, n);

  edge_mfma3_kernel<<<dim3((E + EB - 1) / EB), 256, 0, stream>>>(
      x, pairs, E, W1g, W2T, biasC, P1t, P2t, scores);

  attn_fused_kernel<<<dim3((n + 3) / 4), 256, 0, stream>>>(
      offs, pairs, scores, q_t, k8, v_t, agg, n);

  c2_mfma_kernel<<<dim3((n + 63) / 64, 4), 256, 0, stream>>>(c1, cw2bf, cb2, c2, n);

  hipMemsetAsync((float*)d_out + (size_t)n * 128, 0, (size_t)n * 3 * 4, stream);
  final_mfma_kernel<<<dim3((n + 63) / 64, 2), 256, 0, stream>>>(agg, c2, wcomb, bcomb,
                                                                (float*)d_out, n);
}

// Round 8
// 617.865 us; speedup vs baseline: 1.0193x; 1.0193x over previous
//
#include <hip/hip_runtime.h>

typedef unsigned int uint;
typedef unsigned short ushort;
typedef unsigned char uchar;
typedef __attribute__((ext_vector_type(8))) short bf16x8;
typedef __attribute__((ext_vector_type(8))) ushort ushort8;
typedef __attribute__((ext_vector_type(4))) float f32x4;

// ---------- helpers ----------
__device__ __forceinline__ float silu_fast(float t) {
  return t * __builtin_amdgcn_rcpf(1.f + __expf(-t));
}
__device__ __forceinline__ float bf2f(ushort u) {
  union { uint i; float f; } v; v.i = ((uint)u) << 16; return v.f;
}
__device__ __forceinline__ float bf2f_lo(uint u) {
  union { uint i; float f; } v; v.i = u << 16; return v.f;
}
__device__ __forceinline__ float bf2f_hi(uint u) {
  union { uint i; float f; } v; v.i = u & 0xffff0000u; return v.f;
}
__device__ __forceinline__ ushort f2bf(float f) {
  union { float f; uint i; } v; v.f = f;
  uint r = (v.i + 0x7fffu + ((v.i >> 16) & 1u)) >> 16;
  return (ushort)r;
}
__device__ __forceinline__ uint cvtpk_bf(float a, float b) {
  uint r; asm("v_cvt_pk_bf16_f32 %0, %1, %2" : "=v"(r) : "v"(a), "v"(b)); return r;
}
// fp8 e4m3 (OCP) encode, RNE, sat-to-448
__device__ __forceinline__ uchar f2e4m3(float f) {
  uint u = __float_as_uint(f);
  uint s = (u >> 24) & 0x80u;
  uint m = u & 0x7fffffffu;
  if (m >= 0x43f00000u) return (uchar)(s | 0x7e);
  if (m >= 0x3c800000u) {
    uint r = m + 0x7ffffu + ((m >> 20) & 1u);
    uint e = (r >> 23) - 120u;
    if (e > 15u) return (uchar)(s | 0x7e);
    return (uchar)(s | (e << 3) | ((r >> 20) & 7u));
  }
  float az = __uint_as_float(m);
  uint k = (uint)__float2int_rn(az * 512.f);
  return (uchar)(s | k);
}
__device__ __forceinline__ uint pk4_e4m3(float4 v) {
  return (uint)f2e4m3(v.x) | ((uint)f2e4m3(v.y) << 8)
       | ((uint)f2e4m3(v.z) << 16) | ((uint)f2e4m3(v.w) << 24);
}
// decode WITHOUT the 2^120 scale (folded into qf)
__device__ __forceinline__ float e4m3_raw(uint b) {
  return __uint_as_float(((b & 0x80u) << 24) | ((b & 0x7fu) << 20));
}

// ---------- mega prep: h2bf | c1 | wnode | W1g | W2T | wcomb | cw2bf | count ----------
__global__ __launch_bounds__(256) void mega_prep(
    const float* __restrict__ h, const float* __restrict__ x,
    const int* __restrict__ ei,
    const float* __restrict__ wq, const float* __restrict__ wk, const float* __restrict__ wv,
    const float* __restrict__ bq, const float* __restrict__ bk, const float* __restrict__ bv,
    const float* __restrict__ ew1, const float* __restrict__ eb1,
    const float* __restrict__ pw1, const float* __restrict__ pb1,
    const float* __restrict__ ew2, const float* __restrict__ eww,
    const float* __restrict__ eb2, const float* __restrict__ ewb,
    const float* __restrict__ pw2, const float* __restrict__ pb2,
    const float* __restrict__ wo, const float* __restrict__ cw3,
    const float* __restrict__ bo, const float* __restrict__ cb3,
    const float* __restrict__ cw1, const float* __restrict__ cb1,
    const float* __restrict__ cw2,
    ushort* __restrict__ h_bf, ushort* __restrict__ c1,
    ushort* __restrict__ wnode, float* __restrict__ bqkv,
    short* __restrict__ W1g,
    short* __restrict__ W2T, float* __restrict__ biasC,
    ushort* __restrict__ wcomb, float* __restrict__ bcomb,
    ushort* __restrict__ cw2bf, int* __restrict__ cnt,
    int n, int E,
    int o1, int o2, int o3, int o4, int o5, int o6, int o7)
{
  int b = blockIdx.x, tid = threadIdx.x;
  if (b < o1) {                       // h -> bf16, 4/thread
    int idx = b * 256 + tid;
    if (idx * 4 < n * 128) {
      float4 v = *(const float4*)(h + idx * 4);
      ushort4 o; o.x = f2bf(v.x); o.y = f2bf(v.y); o.z = f2bf(v.z); o.w = f2bf(v.w);
      *(ushort4*)(h_bf + idx * 4) = o;
    }
  } else if (b < o2) {                // c1 = silu(x@cw1^T+cb1) bf16, 4/thread
    int idx = (b - o1) * 256 + tid;
    if (idx < n * 64) {
      int node = idx >> 6, j = (idx & 63) * 4;
      float x0 = x[node * 3], x1 = x[node * 3 + 1], x2 = x[node * 3 + 2];
      ushort4 o;
#pragma unroll
      for (int jj = 0; jj < 4; ++jj) {
        float t = fmaf(x2, cw1[(j + jj) * 3 + 2],
                  fmaf(x1, cw1[(j + jj) * 3 + 1],
                  fmaf(x0, cw1[(j + jj) * 3 + 0], cb1[j + jj])));
        ((ushort*)&o)[jj] = f2bf(silu_fast(t));
      }
      *(ushort4*)(c1 + (size_t)node * 256 + j) = o;
    }
  } else if (b < o3) {                // wnode [2048][128] bf16 + bqkv
    int idx = (b - o2) * 256 + tid;
    if (idx < 2048 * 128) {
      int j = idx >> 7, k = idx & 127;
      float v;
      if (j < 512)       v = wq[j * 128 + k];
      else if (j < 1024) v = wk[(j - 512) * 128 + k];
      else if (j < 1536) v = wv[(j - 1024) * 128 + k];
      else if (j < 1792) v = ew1[(j - 1536) * 263 + k];
      else               v = ew1[(j - 1792) * 263 + 128 + k];
      wnode[idx] = f2bf(v);
      if (idx < 1536)
        bqkv[idx] = (idx < 512) ? bq[idx] : (idx < 1024) ? bk[idx - 512] : bv[idx - 1024];
    }
  } else if (b < o4) {                // W1g [512 n][32 k]: geom+bias projection
    int idx = (b - o3) * 256 + tid;
    if (idx < 512 * 32) {
      int nn = idx >> 5, k = idx & 31;
      float v = 0.f;
      if (nn < 256) {
        if (k == 0)      v = eb1[nn];
        else if (k < 8)  v = ew1[nn * 263 + 256 + (k - 1)];   // rd, xr(3), xc(3)
      } else {
        int p = nn - 256;
        if (k == 0)           v = pb1[p];
        else if (k >= 2 && k < 8) v = pw1[p * 6 + (k - 2)];   // xr(3), xc(3)
      }
      W1g[idx] = (short)f2bf(v);
    }
  } else if (b < o5) {                // W2T [16][512] + biasC
    int idx = (b - o4) * 256 + tid;
    if (idx < 16 * 512) {
      int hh = idx >> 9, k = idx & 511;
      float v = 0.f;
      if (hh < 8) {
        if (k < 256) {
          float s = 0.f;
          for (int j = 0; j < 256; ++j) s += eww[hh * 256 + j] * ew2[j * 256 + k];
          v = s;
        } else v = pw2[hh * 256 + (k - 256)];
      }
      W2T[idx] = (short)f2bf(v);
      if (idx < 16) {
        float bb = 0.f;
        if (idx < 8) {
          float s = 0.f;
          for (int j = 0; j < 256; ++j) s += eww[idx * 256 + j] * eb2[j];
          bb = s + ewb[idx] + pb2[idx];
        }
        biasC[idx] = bb;
      }
    }
  } else if (b < o6) {                // wcomb [128][768] + bcomb
    int idx = (b - o5) * 256 + tid;
    if (idx < 128 * 768) {
      int j = idx / 768, k = idx % 768;
      float v = (k < 512) ? wo[j * 512 + k] : cw3[j * 256 + (k - 512)];
      wcomb[idx] = f2bf(v);
      if (idx < 128) bcomb[idx] = bo[idx] + cb3[idx];
    }
  } else if (b < o7) {                // cw2 bf16
    int idx = (b - o6) * 256 + tid;
    if (idx < 256 * 256) cw2bf[idx] = f2bf(cw2[idx]);
  } else {                            // count (CSR degree)
    int e = (b - o7) * 256 + tid;
    if (e < E) atomicAdd(&cnt[ei[e]], 1);
  }
}

// ---------- node projections: 1 jb per block (y=32), LDS-coalesced stores ----------
__global__ __launch_bounds__(256) void nodeproj_kernel(
    const ushort* __restrict__ h_bf,    // [n][128] bf16
    const ushort* __restrict__ wnode,   // [2048][128]
    const float* __restrict__ bqkv,     // [1536]
    ushort* __restrict__ q_t, uchar* __restrict__ k8, ushort* __restrict__ v_t,
    ushort* __restrict__ P1t, ushort* __restrict__ P2t,
    int n)
{
  __shared__ float oS[64 * 68];         // 17,408 B
  int tid = threadIdx.x;
  int lane = tid & 63, w = tid >> 6;
  int l15 = lane & 15, l4 = lane >> 4;
  int m0 = blockIdx.x * 64;
  int jb = blockIdx.y;                  // 0..31
  int mrow = m0 + w * 16 + l15;
  int mr = (mrow < n) ? mrow : (n - 1);

  bf16x8 hf[4];
#pragma unroll
  for (int ks = 0; ks < 4; ++ks)
    hf[ks] = *(const bf16x8*)(h_bf + (size_t)mr * 128 + ks * 32 + l4 * 8);

  f32x4 acc[4];
#pragma unroll
  for (int nf = 0; nf < 4; ++nf) acc[nf] = (f32x4){0.f, 0.f, 0.f, 0.f};
#pragma unroll
  for (int nf = 0; nf < 4; ++nf)
#pragma unroll
    for (int ks = 0; ks < 4; ++ks) {
      bf16x8 wf = *(const bf16x8*)(wnode + (size_t)(jb * 64 + nf * 16 + l15) * 128 + ks * 32 + l4 * 8);
      acc[nf] = __builtin_amdgcn_mfma_f32_16x16x32_bf16(wf, hf[ks], acc[nf], 0, 0, 0);
    }
  // stage: oS[node_local][col_local]
#pragma unroll
  for (int nf = 0; nf < 4; ++nf)
    *(f32x4*)(oS + (w * 16 + l15) * 68 + nf * 16 + l4 * 4) = acc[nf];
  __syncthreads();
  // coalesced writers: 4 threads per row, 16 cols each
  int row = tid >> 2, cs = (tid & 3) * 16;
  int gr = m0 + row;
  if (gr < n) {
    float4 o0 = *(const float4*)(oS + row * 68 + cs);
    float4 o1 = *(const float4*)(oS + row * 68 + cs + 4);
    float4 o2 = *(const float4*)(oS + row * 68 + cs + 8);
    float4 o3 = *(const float4*)(oS + row * 68 + cs + 12);
    int gc = jb * 64 + cs;
    if (jb < 24) {
      float4 b0 = *(const float4*)(bqkv + gc);
      float4 b1 = *(const float4*)(bqkv + gc + 4);
      float4 b2 = *(const float4*)(bqkv + gc + 8);
      float4 b3 = *(const float4*)(bqkv + gc + 12);
      o0.x += b0.x; o0.y += b0.y; o0.z += b0.z; o0.w += b0.w;
      o1.x += b1.x; o1.y += b1.y; o1.z += b1.z; o1.w += b1.w;
      o2.x += b2.x; o2.y += b2.y; o2.z += b2.z; o2.w += b2.w;
      o3.x += b3.x; o3.y += b3.y; o3.z += b3.z; o3.w += b3.w;
      if (jb < 8) {
        uint4 s0 = {cvtpk_bf(o0.x,o0.y), cvtpk_bf(o0.z,o0.w), cvtpk_bf(o1.x,o1.y), cvtpk_bf(o1.z,o1.w)};
        uint4 s1 = {cvtpk_bf(o2.x,o2.y), cvtpk_bf(o2.z,o2.w), cvtpk_bf(o3.x,o3.y), cvtpk_bf(o3.z,o3.w)};
        *(uint4*)(q_t + (size_t)gr * 512 + gc) = s0;
        *(uint4*)(q_t + (size_t)gr * 512 + gc + 8) = s1;
      } else if (jb < 16) {
        uint4 st = {pk4_e4m3(o0), pk4_e4m3(o1), pk4_e4m3(o2), pk4_e4m3(o3)};
        *(uint4*)(k8 + (size_t)gr * 512 + (gc - 512)) = st;
      } else {
        uint4 s0 = {cvtpk_bf(o0.x,o0.y), cvtpk_bf(o0.z,o0.w), cvtpk_bf(o1.x,o1.y), cvtpk_bf(o1.z,o1.w)};
        uint4 s1 = {cvtpk_bf(o2.x,o2.y), cvtpk_bf(o2.z,o2.w), cvtpk_bf(o3.x,o3.y), cvtpk_bf(o3.z,o3.w)};
        *(uint4*)(v_t + (size_t)gr * 512 + (gc - 1024)) = s0;
        *(uint4*)(v_t + (size_t)gr * 512 + (gc - 1024) + 8) = s1;
      }
    } else {
      int pc = (jb & 3) * 64 + cs;
      uint4 s0 = {cvtpk_bf(o0.x,o0.y), cvtpk_bf(o0.z,o0.w), cvtpk_bf(o1.x,o1.y), cvtpk_bf(o1.z,o1.w)};
      uint4 s1 = {cvtpk_bf(o2.x,o2.y), cvtpk_bf(o2.z,o2.w), cvtpk_bf(o3.x,o3.y), cvtpk_bf(o3.z,o3.w)};
      ushort* P = (jb < 28) ? P1t : P2t;
      *(uint4*)(P + (size_t)gr * 256 + pc) = s0;
      *(uint4*)(P + (size_t)gr * 256 + pc + 8) = s1;
    }
  }
}

// ---------- CSR scan + fill ----------
__global__ __launch_bounds__(1024) void scan_kernel(int* __restrict__ cnt,
                                                    int* __restrict__ offs, int n) {
  __shared__ int part[1024];
  int t = threadIdx.x;
  int chunk = (n + 1023) >> 10;
  int s = t * chunk, e = min(s + chunk, n);
  int sum = 0;
  for (int i = s; i < e; ++i) sum += cnt[i];
  part[t] = sum;
  __syncthreads();
  for (int off = 1; off < 1024; off <<= 1) {
    int v = (t >= off) ? part[t - off] : 0;
    __syncthreads();
    part[t] += v;
    __syncthreads();
  }
  int run = (t == 0) ? 0 : part[t - 1];
  for (int i = s; i < e; ++i) {
    int c = cnt[i];
    offs[i] = run;
    cnt[i] = run;
    run += c;
  }
  if (t == 1023) offs[n] = run;
}

// pairs[slot] = (col, row | (masked ? 0x80000000 : 0))
__global__ __launch_bounds__(256) void fill_kernel(const int* __restrict__ ei,
                                                   const int* __restrict__ mask,
                                                   int* __restrict__ cursor,
                                                   int2* __restrict__ pairs, int E) {
  int e = blockIdx.x * 256 + threadIdx.x;
  if (e < E) {
    int r = ei[e];
    int p = atomicAdd(&cursor[r], 1);
    int rm = r | (mask[e] ? 0 : (int)0x80000000u);
    pairs[p] = make_int2(ei[E + e], rm);
  }
}

// ---------- edge MLP v3: factorized, CSR-ordered ----------
#define EB 64
#define GS 40       // geom stride (shorts)
#define TS 72       // t1 stride (shorts)

__global__ __launch_bounds__(256) void edge_mfma3_kernel(
    const float* __restrict__ x,
    const int2* __restrict__ pairs, int E,
    const short* __restrict__ W1g,      // [512][32]
    const short* __restrict__ W2T, const float* __restrict__ biasC,
    const ushort* __restrict__ P1t, const ushort* __restrict__ P2t,
    float* __restrict__ scores)
{
  __shared__ short geomL[EB * GS];      // 5 KB
  __shared__ int2 rcL[EB];              // 0.5 KB
  __shared__ short T1[4 * EB * TS];     // 36,864 B
  float* slab = (float*)T1;             // overlay after layer2

  int tid = threadIdx.x;
  int lane = tid & 63, w = tid >> 6;
  int l15 = lane & 15, l4 = lane >> 4;
  int eb0 = blockIdx.x * EB;

  if (tid < EB) {
    int i = min(eb0 + tid, E - 1);
    int2 pr = pairs[i];
    rcL[tid] = pr;
    int c = pr.x, r = pr.y & 0x7fffffff;
    float xr0 = x[r*3], xr1 = x[r*3+1], xr2 = x[r*3+2];
    float xc0 = x[c*3], xc1 = x[c*3+1], xc2 = x[c*3+2];
    float d0 = xr0-xc0, d1 = xr1-xc1, d2 = xr2-xc2;
    bf16x8 g;
    g[0] = (short)0x3F80;               // 1.0 (bias input)
    g[1] = (short)f2bf(d0*d0 + d1*d1 + d2*d2);
    g[2] = (short)f2bf(xr0); g[3] = (short)f2bf(xr1); g[4] = (short)f2bf(xr2);
    g[5] = (short)f2bf(xc0); g[6] = (short)f2bf(xc1); g[7] = (short)f2bf(xc2);
    bf16x8 z = {0,0,0,0,0,0,0,0};
    *(bf16x8*)(geomL + tid * GS) = g;
    *(bf16x8*)(geomL + tid * GS + 8) = z;
    *(bf16x8*)(geomL + tid * GS + 16) = z;
    *(bf16x8*)(geomL + tid * GS + 24) = z;
    *(bf16x8*)(geomL + tid * GS + 32) = z;
  }
  __syncthreads();

  int rr[4], cc[4];
  bf16x8 bE[4];
#pragma unroll
  for (int ef = 0; ef < 4; ++ef) {
    int2 pr = rcL[ef * 16 + l15];
    cc[ef] = pr.x; rr[ef] = pr.y & 0x7fffffff;
    bE[ef] = *(const bf16x8*)(geomL + (ef * 16 + l15) * GS + l4 * 8);
  }

  f32x4 sacc[4];
#pragma unroll
  for (int ef = 0; ef < 4; ++ef) sacc[ef] = (f32x4){0.f, 0.f, 0.f, 0.f};

  short* t1w = T1 + w * (EB * TS);

#pragma unroll
  for (int cch = 0; cch < 2; ++cch) {
    const int n0 = cch ? (256 + w * 64) : (w * 64);
    f32x4 acc[4][4];
#pragma unroll
    for (int mf = 0; mf < 4; ++mf) {
      bf16x8 aW = *(const bf16x8*)(W1g + (size_t)(n0 + mf * 16 + l15) * 32 + l4 * 8);
#pragma unroll
      for (int ef = 0; ef < 4; ++ef)
        acc[mf][ef] = __builtin_amdgcn_mfma_f32_16x16x32_bf16(
            aW, bE[ef], (f32x4){0.f, 0.f, 0.f, 0.f}, 0, 0, 0);
    }
    if (cch == 0) {
#pragma unroll
      for (int mf = 0; mf < 4; ++mf) {
        int colb = n0 + mf * 16 + l4 * 4;
        uint2 g1[4], g2[4];
#pragma unroll
        for (int ef = 0; ef < 4; ++ef) {
          g1[ef] = *(const uint2*)(P1t + (size_t)rr[ef] * 256 + colb);
          g2[ef] = *(const uint2*)(P2t + (size_t)cc[ef] * 256 + colb);
        }
#pragma unroll
        for (int ef = 0; ef < 4; ++ef) {
          f32x4 a = acc[mf][ef];
          a[0] += bf2f_lo(g1[ef].x) + bf2f_lo(g2[ef].x);
          a[1] += bf2f_hi(g1[ef].x) + bf2f_hi(g2[ef].x);
          a[2] += bf2f_lo(g1[ef].y) + bf2f_lo(g2[ef].y);
          a[3] += bf2f_hi(g1[ef].y) + bf2f_hi(g2[ef].y);
          acc[mf][ef] = a;
        }
      }
    }
#pragma unroll
    for (int mf = 0; mf < 4; ++mf) {
      int nl = mf * 16 + l4 * 4;
#pragma unroll
      for (int ef = 0; ef < 4; ++ef) {
        int e = ef * 16 + l15;
        f32x4 v = acc[mf][ef];
        float s0 = silu_fast(v[0]);
        float s1 = silu_fast(v[1]);
        float s2 = silu_fast(v[2]);
        float s3 = silu_fast(v[3]);
        uint2 pk;
        pk.x = cvtpk_bf(s0, s1);
        pk.y = cvtpk_bf(s2, s3);
        *(uint2*)(t1w + e * TS + nl) = pk;
      }
    }
#pragma unroll
    for (int ks2 = 0; ks2 < 2; ++ks2) {
      bf16x8 bW2 = *(const bf16x8*)(W2T + (size_t)l15 * 512 + n0 + ks2 * 32 + l4 * 8);
#pragma unroll
      for (int ef = 0; ef < 4; ++ef) {
        bf16x8 aT = *(const bf16x8*)(t1w + (ef * 16 + l15) * TS + ks2 * 32 + l4 * 8);
        sacc[ef] = __builtin_amdgcn_mfma_f32_16x16x32_bf16(aT, bW2, sacc[ef], 0, 0, 0);
      }
    }
  }
  __syncthreads();
#pragma unroll
  for (int ef = 0; ef < 4; ++ef)
#pragma unroll
    for (int i = 0; i < 4; ++i)
      slab[(w * EB + ef * 16 + l4 * 4 + i) * 16 + l15] = sacc[ef][i];
  __syncthreads();
  for (int t = tid; t < EB * 8; t += 256) {
    int e = t >> 3, hh = t & 7;
    float s = biasC[hh]
            + slab[(0 * EB + e) * 16 + hh] + slab[(1 * EB + e) * 16 + hh]
            + slab[(2 * EB + e) * 16 + hh] + slab[(3 * EB + e) * 16 + hh];
    if (rcL[e].y < 0) s = -1e9f;
    if (eb0 + e < E) scores[(size_t)(eb0 + e) * 8 + hh] = s;
  }
}

// ---------- fused QK + softmax + aggregation (no-max softmax, 2-wide pipeline) ----------
__global__ __launch_bounds__(256) void attn_fused_kernel(
    const int* __restrict__ offs,
    const int2* __restrict__ pairs,
    const float* __restrict__ scores,
    const ushort* __restrict__ q_t,
    const uchar* __restrict__ k8,
    const ushort* __restrict__ v_t,
    ushort* __restrict__ agg, int n)
{
  int node = blockIdx.x * 4 + (threadIdx.x >> 6);
  if (node >= n) return;
  int lane = threadIdx.x & 63;
  int hh = lane >> 3;
  int start = offs[node], end = offs[node + 1];

  bf16x8 qv = *(const bf16x8*)(q_t + (size_t)node * 512 + lane * 8);
  float qf[8];
#pragma unroll
  for (int j = 0; j < 8; ++j) qf[j] = bf2f((ushort)qv[j]) * 0x1p+120f;

  float ssum = 0.f;
  float acc[8];
#pragma unroll
  for (int j = 0; j < 8; ++j) acc[j] = 0.f;

  if (start < end) {
    int ib = min(start + 1, end - 1);
    int c0 = pairs[start].x, c1 = pairs[ib].x;
    uint2 kwa = *(const uint2*)(k8 + (size_t)c0 * 512 + lane * 8);
    bf16x8 vva = *(const bf16x8*)(v_t + (size_t)c0 * 512 + lane * 8);
    float sma = scores[(size_t)start * 8 + hh];
    uint2 kwb = *(const uint2*)(k8 + (size_t)c1 * 512 + lane * 8);
    bf16x8 vvb = *(const bf16x8*)(v_t + (size_t)c1 * 512 + lane * 8);
    float smb = scores[(size_t)ib * 8 + hh];

    for (int i = start; i < end; i += 2) {
      uint2 k0 = kwa, k1 = kwb;
      bf16x8 v0 = vva, v1 = vvb;
      float s0 = sma, s1 = smb;
      bool has1 = (i + 1) < end;
      // prefetch next pair
      int j0 = min(i + 2, end - 1), j1 = min(i + 3, end - 1);
      int d0 = pairs[j0].x, d1 = pairs[j1].x;
      kwa = *(const uint2*)(k8 + (size_t)d0 * 512 + lane * 8);
      vva = *(const bf16x8*)(v_t + (size_t)d0 * 512 + lane * 8);
      sma = scores[(size_t)j0 * 8 + hh];
      kwb = *(const uint2*)(k8 + (size_t)d1 * 512 + lane * 8);
      vvb = *(const bf16x8*)(v_t + (size_t)d1 * 512 + lane * 8);
      smb = scores[(size_t)j1 * 8 + hh];

      float dot0 = 0.f, dot1 = 0.f;
#pragma unroll
      for (int j = 0; j < 4; ++j) {
        dot0 = fmaf(qf[j],     e4m3_raw((k0.x >> (8 * j)) & 0xffu), dot0);
        dot0 = fmaf(qf[4 + j], e4m3_raw((k0.y >> (8 * j)) & 0xffu), dot0);
        dot1 = fmaf(qf[j],     e4m3_raw((k1.x >> (8 * j)) & 0xffu), dot1);
        dot1 = fmaf(qf[4 + j], e4m3_raw((k1.y >> (8 * j)) & 0xffu), dot1);
      }
      dot0 += __shfl_xor(dot0, 1); dot0 += __shfl_xor(dot0, 2); dot0 += __shfl_xor(dot0, 4);
      dot1 += __shfl_xor(dot1, 1); dot1 += __shfl_xor(dot1, 2); dot1 += __shfl_xor(dot1, 4);
      float sc0 = (s0 < -5e8f) ? -1e9f : fmaf(dot0, 0.125f, s0);
      float sc1 = (!has1 || s1 < -5e8f) ? -1e9f : fmaf(dot1, 0.125f, s1);
      float e0 = __expf(sc0);
      float e1 = __expf(sc1);
      ssum += e0 + e1;
#pragma unroll
      for (int j = 0; j < 8; ++j) {
        acc[j] = fmaf(e0, bf2f((ushort)v0[j]), acc[j]);
        acc[j] = fmaf(e1, bf2f((ushort)v1[j]), acc[j]);
      }
    }
  }
  float inv = __builtin_amdgcn_rcpf(ssum + 1e-8f);
  ushort8 ov;
#pragma unroll
  for (int j = 0; j < 8; ++j) ov[j] = f2bf(acc[j] * inv);
  *(ushort8*)(agg + (size_t)node * 512 + lane * 8) = ov;
}

// ---------- coord layer 2 via MFMA: c2 = silu(c1 @ cw2^T + cb2) bf16 ----------
__global__ __launch_bounds__(256) void c2_mfma_kernel(const ushort* __restrict__ c1,
                                                      const ushort* __restrict__ cw2bf,
                                                      const float* __restrict__ cb2,
                                                      ushort* __restrict__ c2, int n) {
  __shared__ float oS[64 * 68];
  int tid = threadIdx.x;
  int lane = tid & 63, w = tid >> 6;
  int l15 = lane & 15, l4 = lane >> 4;
  int m0 = blockIdx.x * 64;
  int n0 = blockIdx.y * 64 + w * 16;

  f32x4 acc[4];
#pragma unroll
  for (int mf = 0; mf < 4; ++mf) acc[mf] = (f32x4){0.f, 0.f, 0.f, 0.f};
#pragma unroll
  for (int ks = 0; ks < 8; ++ks) {
    bf16x8 bW = *(const bf16x8*)(cw2bf + (size_t)(n0 + l15) * 256 + ks * 32 + l4 * 8);
#pragma unroll
    for (int mf = 0; mf < 4; ++mf) {
      int gr = m0 + mf * 16 + l15; if (gr >= n) gr = n - 1;
      bf16x8 aH = *(const bf16x8*)(c1 + (size_t)gr * 256 + ks * 32 + l4 * 8);
      acc[mf] = __builtin_amdgcn_mfma_f32_16x16x32_bf16(aH, bW, acc[mf], 0, 0, 0);
    }
  }
#pragma unroll
  for (int mf = 0; mf < 4; ++mf)
#pragma unroll
    for (int i = 0; i < 4; ++i)
      oS[(mf * 16 + l4 * 4 + i) * 68 + w * 16 + l15] = acc[mf][i];
  __syncthreads();
  {
    int row = tid >> 2, cs = (tid & 3) * 16;
    int gr = m0 + row;
    if (gr < n) {
      int gc = blockIdx.y * 64 + cs;
      ushort8 o0, o1;
#pragma unroll
      for (int j = 0; j < 8; ++j) o0[j] = f2bf(silu_fast(oS[row * 68 + cs + j] + cb2[gc + j]));
#pragma unroll
      for (int j = 0; j < 8; ++j) o1[j] = f2bf(silu_fast(oS[row * 68 + cs + 8 + j] + cb2[gc + 8 + j]));
      *(ushort8*)(c2 + (size_t)gr * 256 + gc) = o0;
      *(ushort8*)(c2 + (size_t)gr * 256 + gc + 8) = o1;
    }
  }
}

// ---------- final fused out GEMM: out[n][128] = [agg|c2] @ wcomb^T + bcomb ----------
__global__ __launch_bounds__(256) void final_mfma_kernel(const ushort* __restrict__ agg,
                                                         const ushort* __restrict__ c2,
                                                         const ushort* __restrict__ wcomb,
                                                         const float* __restrict__ bcomb,
                                                         float* __restrict__ out, int n) {
  __shared__ float oS[64 * 68];
  int tid = threadIdx.x;
  int lane = tid & 63, w = tid >> 6;
  int l15 = lane & 15, l4 = lane >> 4;
  int m0 = blockIdx.x * 64;
  int jb = blockIdx.y;
  int n0 = jb * 64 + w * 16;

  f32x4 acc[4];
#pragma unroll
  for (int mf = 0; mf < 4; ++mf) acc[mf] = (f32x4){0.f, 0.f, 0.f, 0.f};
#pragma unroll
  for (int ks = 0; ks < 24; ++ks) {
    bf16x8 bW = *(const bf16x8*)(wcomb + (size_t)(n0 + l15) * 768 + ks * 32 + l4 * 8);
#pragma unroll
    for (int mf = 0; mf < 4; ++mf) {
      int gr = m0 + mf * 16 + l15; if (gr >= n) gr = n - 1;
      const ushort* ap = (ks < 16) ? (agg + (size_t)gr * 512 + ks * 32)
                                   : (c2 + (size_t)gr * 256 + (ks - 16) * 32);
      bf16x8 aH = *(const bf16x8*)(ap + l4 * 8);
      acc[mf] = __builtin_amdgcn_mfma_f32_16x16x32_bf16(aH, bW, acc[mf], 0, 0, 0);
    }
  }
#pragma unroll
  for (int mf = 0; mf < 4; ++mf)
#pragma unroll
    for (int i = 0; i < 4; ++i)
      oS[(mf * 16 + l4 * 4 + i) * 68 + w * 16 + l15] = acc[mf][i];
  __syncthreads();
  {
    int row = tid >> 2, cs = (tid & 3) * 16;
    int gr = m0 + row;
    if (gr < n) {
      int gc = jb * 64 + cs;
#pragma unroll
      for (int g = 0; g < 4; ++g) {
        float4 o;
        o.x = oS[row * 68 + cs + g * 4 + 0] + bcomb[gc + g * 4 + 0];
        o.y = oS[row * 68 + cs + g * 4 + 1] + bcomb[gc + g * 4 + 1];
        o.z = oS[row * 68 + cs + g * 4 + 2] + bcomb[gc + g * 4 + 2];
        o.w = oS[row * 68 + cs + g * 4 + 3] + bcomb[gc + g * 4 + 3];
        *(float4*)(out + (size_t)gr * 128 + gc + g * 4) = o;
      }
    }
  }
}

// ---------- launch ----------
extern "C" void kernel_launch(void* const* d_in, const int* in_sizes, int n_in,
                              void* d_out, int out_size, void* d_ws, size_t ws_size,
                              hipStream_t stream) {
  const float* h   = (const float*)d_in[0];
  const float* x   = (const float*)d_in[1];
  const int*   ei  = (const int*)d_in[2];
  const int*   mask= (const int*)d_in[3];
  const float* wq  = (const float*)d_in[4];
  const float* bq  = (const float*)d_in[5];
  const float* wk  = (const float*)d_in[6];
  const float* bk  = (const float*)d_in[7];
  const float* wv  = (const float*)d_in[8];
  const float* bv  = (const float*)d_in[9];
  const float* wo  = (const float*)d_in[10];
  const float* bo  = (const float*)d_in[11];
  const float* pw1 = (const float*)d_in[12];
  const float* pb1 = (const float*)d_in[13];
  const float* pw2 = (const float*)d_in[14];
  const float* pb2 = (const float*)d_in[15];
  const float* ew1 = (const float*)d_in[16];
  const float* eb1 = (const float*)d_in[17];
  const float* ew2 = (const float*)d_in[18];
  const float* eb2 = (const float*)d_in[19];
  const float* eww = (const float*)d_in[20];
  const float* ewb = (const float*)d_in[21];
  const float* cw1 = (const float*)d_in[22];
  const float* cb1 = (const float*)d_in[23];
  const float* cw2 = (const float*)d_in[24];
  const float* cb2 = (const float*)d_in[25];
  const float* cw3 = (const float*)d_in[26];
  const float* cb3 = (const float*)d_in[27];

  int n = in_sizes[0] / 128;
  int E = in_sizes[3];

  char* wptr = (char*)d_ws;
  auto alloc = [&](size_t bytes) {
    char* p = wptr;
    wptr += (bytes + 255) & ~(size_t)255;
    return p;
  };
  ushort* q_t   = (ushort*)alloc((size_t)n * 512 * 2);   // also reused as agg
  uchar*  k8    = (uchar*)alloc((size_t)n * 512);
  ushort* v_t   = (ushort*)alloc((size_t)n * 512 * 2);
  ushort* P1t   = (ushort*)alloc((size_t)n * 256 * 2);
  ushort* P2t   = (ushort*)alloc((size_t)n * 256 * 2);
  ushort* h_bf  = (ushort*)alloc((size_t)n * 128 * 2);
  float* scores = (float*)alloc((size_t)E * 8 * 4);
  ushort* c1    = (ushort*)alloc((size_t)n * 256 * 2);
  ushort* c2    = (ushort*)alloc((size_t)n * 256 * 2);
  ushort* wnode = (ushort*)alloc((size_t)2048 * 128 * 2);
  float* bqkv   = (float*)alloc((size_t)1536 * 4);
  short* W1g    = (short*)alloc((size_t)512 * 32 * 2);
  short* W2T    = (short*)alloc((size_t)16 * 512 * 2);
  float* biasC  = (float*)alloc((size_t)16 * 4);
  ushort* wcomb = (ushort*)alloc((size_t)128 * 768 * 2);
  float* bcomb  = (float*)alloc((size_t)128 * 4);
  ushort* cw2bf = (ushort*)alloc((size_t)256 * 256 * 2);
  int* offs     = (int*)alloc((size_t)(n + 1) * 4);
  int* cursor   = (int*)alloc((size_t)n * 4);
  int2* pairs   = (int2*)alloc((size_t)E * 8);
  ushort* agg   = q_t;    // overlay: attn reads q[node] before writing agg[node]

  hipMemsetAsync(cursor, 0, (size_t)n * 4, stream);

  // mega-prep segment boundaries
  int b_h2  = (n * 128 / 4 + 255) / 256;
  int b_c1  = (n * 64 + 255) / 256;
  int b_wn  = (2048 * 128) / 256;
  int b_w1  = (512 * 32 + 255) / 256;
  int b_w2  = (16 * 512 + 255) / 256;
  int b_wc  = (128 * 768 + 255) / 256;
  int b_cw  = (256 * 256 + 255) / 256;
  int b_cnt = (E + 255) / 256;
  int o1 = b_h2, o2 = o1 + b_c1, o3 = o2 + b_wn, o4 = o3 + b_w1;
  int o5 = o4 + b_w2, o6 = o5 + b_wc, o7 = o6 + b_cw;
  int total_blocks = o7 + b_cnt;

  mega_prep<<<dim3(total_blocks), 256, 0, stream>>>(
      h, x, ei, wq, wk, wv, bq, bk, bv, ew1, eb1, pw1, pb1, ew2, eww, eb2, ewb,
      pw2, pb2, wo, cw3, bo, cb3, cw1, cb1, cw2,
      h_bf, c1, wnode, bqkv, W1g, W2T, biasC, wcomb, bcomb, cw2bf, cursor,
      n, E, o1, o2, o3, o4, o5, o6, o7);

  scan_kernel<<<dim3(1), 1024, 0, stream>>>(cursor, offs, n);
  fill_kernel<<<dim3((E + 255) / 256), 256, 0, stream>>>(ei, mask, cursor, pairs, E);

  nodeproj_kernel<<<dim3((n + 63) / 64, 32), 256, 0, stream>>>(
      h_bf, wnode, bqkv, q_t, k8, v_t, P1t, P2t, n);

  edge_mfma3_kernel<<<dim3((E + EB - 1) / EB), 256, 0, stream>>>(
      x, pairs, E, W1g, W2T, biasC, P1t, P2t, scores);

  attn_fused_kernel<<<dim3((n + 3) / 4), 256, 0, stream>>>(
      offs, pairs, scores, q_t, k8, v_t, agg, n);

  c2_mfma_kernel<<<dim3((n + 63) / 64, 4), 256, 0, stream>>>(c1, cw2bf, cb2, c2, n);

  hipMemsetAsync((float*)d_out + (size_t)n * 128, 0, (size_t)n * 3 * 4, stream);
  final_mfma_kernel<<<dim3((n + 63) / 64, 2), 256, 0, stream>>>(agg, c2, wcomb, bcomb,
                                                                (float*)d_out, n);
}

// Round 10
// 605.031 us; speedup vs baseline: 1.0409x; 1.0212x over previous
//
#include <hip/hip_runtime.h>

typedef unsigned int uint;
typedef unsigned short ushort;
typedef unsigned char uchar;
typedef __attribute__((ext_vector_type(8))) short bf16x8;
typedef __attribute__((ext_vector_type(8))) ushort ushort8;
typedef __attribute__((ext_vector_type(4))) float f32x4;
typedef __attribute__((ext_vector_type(4))) uint u32x4;

// ---------- helpers ----------
__device__ __forceinline__ float silu_fast(float t) {
  return t * __builtin_amdgcn_rcpf(1.f + __expf(-t));
}
__device__ __forceinline__ float bf2f(ushort u) {
  union { uint i; float f; } v; v.i = ((uint)u) << 16; return v.f;
}
__device__ __forceinline__ float bf2f_lo(uint u) {
  union { uint i; float f; } v; v.i = u << 16; return v.f;
}
__device__ __forceinline__ float bf2f_hi(uint u) {
  union { uint i; float f; } v; v.i = u & 0xffff0000u; return v.f;
}
__device__ __forceinline__ ushort f2bf(float f) {
  union { float f; uint i; } v; v.f = f;
  uint r = (v.i + 0x7fffu + ((v.i >> 16) & 1u)) >> 16;
  return (ushort)r;
}
__device__ __forceinline__ uint cvtpk_bf(float a, float b) {
  uint r; asm("v_cvt_pk_bf16_f32 %0, %1, %2" : "=v"(r) : "v"(a), "v"(b)); return r;
}
// fp8 e4m3 (OCP) encode, RNE, sat-to-448
__device__ __forceinline__ uchar f2e4m3(float f) {
  uint u = __float_as_uint(f);
  uint s = (u >> 24) & 0x80u;
  uint m = u & 0x7fffffffu;
  if (m >= 0x43f00000u) return (uchar)(s | 0x7e);
  if (m >= 0x3c800000u) {
    uint r = m + 0x7ffffu + ((m >> 20) & 1u);
    uint e = (r >> 23) - 120u;
    if (e > 15u) return (uchar)(s | 0x7e);
    return (uchar)(s | (e << 3) | ((r >> 20) & 7u));
  }
  float az = __uint_as_float(m);
  uint k = (uint)__float2int_rn(az * 512.f);
  return (uchar)(s | k);
}
__device__ __forceinline__ uint pk4_e4m3(float4 v) {
  return (uint)f2e4m3(v.x) | ((uint)f2e4m3(v.y) << 8)
       | ((uint)f2e4m3(v.z) << 16) | ((uint)f2e4m3(v.w) << 24);
}
// decode WITHOUT the 2^120 scale (folded into qf)
__device__ __forceinline__ float e4m3_raw(uint b) {
  return __uint_as_float(((b & 0x80u) << 24) | ((b & 0x7fu) << 20));
}

// ---------- mega prep: h2bf | c1 | wnode | W1g | W2T | wcomb | cw2bf | zout | count ----------
__global__ __launch_bounds__(256) void mega_prep(
    const float* __restrict__ h, const float* __restrict__ x,
    const int* __restrict__ ei,
    const float* __restrict__ wq, const float* __restrict__ wk, const float* __restrict__ wv,
    const float* __restrict__ bq, const float* __restrict__ bk, const float* __restrict__ bv,
    const float* __restrict__ ew1, const float* __restrict__ eb1,
    const float* __restrict__ pw1, const float* __restrict__ pb1,
    const float* __restrict__ ew2, const float* __restrict__ eww,
    const float* __restrict__ eb2, const float* __restrict__ ewb,
    const float* __restrict__ pw2, const float* __restrict__ pb2,
    const float* __restrict__ wo, const float* __restrict__ cw3,
    const float* __restrict__ bo, const float* __restrict__ cb3,
    const float* __restrict__ cw1, const float* __restrict__ cb1,
    const float* __restrict__ cw2,
    ushort* __restrict__ h_bf, ushort* __restrict__ c1,
    ushort* __restrict__ wnode, float* __restrict__ bqkv,
    short* __restrict__ W1g,
    short* __restrict__ W2T, float* __restrict__ biasC,
    ushort* __restrict__ wcomb, float* __restrict__ bcomb,
    ushort* __restrict__ cw2bf, float* __restrict__ out_tail,
    int* __restrict__ cnt,
    int n, int E,
    int o1, int o2, int o3, int o4, int o5, int o6, int o7, int o8)
{
  int b = blockIdx.x, tid = threadIdx.x;
  if (b < o1) {                       // h -> bf16, 4/thread
    int idx = b * 256 + tid;
    if (idx * 4 < n * 128) {
      float4 v = *(const float4*)(h + idx * 4);
      ushort4 o; o.x = f2bf(v.x); o.y = f2bf(v.y); o.z = f2bf(v.z); o.w = f2bf(v.w);
      *(ushort4*)(h_bf + idx * 4) = o;
    }
  } else if (b < o2) {                // c1 = silu(x@cw1^T+cb1) bf16, 4/thread
    int idx = (b - o1) * 256 + tid;
    if (idx < n * 64) {
      int node = idx >> 6, j = (idx & 63) * 4;
      float x0 = x[node * 3], x1 = x[node * 3 + 1], x2 = x[node * 3 + 2];
      ushort4 o;
#pragma unroll
      for (int jj = 0; jj < 4; ++jj) {
        float t = fmaf(x2, cw1[(j + jj) * 3 + 2],
                  fmaf(x1, cw1[(j + jj) * 3 + 1],
                  fmaf(x0, cw1[(j + jj) * 3 + 0], cb1[j + jj])));
        ((ushort*)&o)[jj] = f2bf(silu_fast(t));
      }
      *(ushort4*)(c1 + (size_t)node * 256 + j) = o;
    }
  } else if (b < o3) {                // wnode [2048][128] bf16 + bqkv
    int idx = (b - o2) * 256 + tid;
    if (idx < 2048 * 128) {
      int j = idx >> 7, k = idx & 127;
      float v;
      if (j < 512)       v = wq[j * 128 + k];
      else if (j < 1024) v = wk[(j - 512) * 128 + k];
      else if (j < 1536) v = wv[(j - 1024) * 128 + k];
      else if (j < 1792) v = ew1[(j - 1536) * 263 + k];
      else               v = ew1[(j - 1792) * 263 + 128 + k];
      wnode[idx] = f2bf(v);
      if (idx < 1536)
        bqkv[idx] = (idx < 512) ? bq[idx] : (idx < 1024) ? bk[idx - 512] : bv[idx - 1024];
    }
  } else if (b < o4) {                // W1g [512 n][32 k]: geom+bias projection
    int idx = (b - o3) * 256 + tid;
    if (idx < 512 * 32) {
      int nn = idx >> 5, k = idx & 31;
      float v = 0.f;
      if (nn < 256) {
        if (k == 0)      v = eb1[nn];
        else if (k < 8)  v = ew1[nn * 263 + 256 + (k - 1)];   // rd, xr(3), xc(3)
      } else {
        int p = nn - 256;
        if (k == 0)           v = pb1[p];
        else if (k >= 2 && k < 8) v = pw1[p * 6 + (k - 2)];   // xr(3), xc(3)
      }
      W1g[idx] = (short)f2bf(v);
    }
  } else if (b < o5) {                // W2T [16][512] + biasC
    int idx = (b - o4) * 256 + tid;
    if (idx < 16 * 512) {
      int hh = idx >> 9, k = idx & 511;
      float v = 0.f;
      if (hh < 8) {
        if (k < 256) {
          float s = 0.f;
          for (int j = 0; j < 256; ++j) s += eww[hh * 256 + j] * ew2[j * 256 + k];
          v = s;
        } else v = pw2[hh * 256 + (k - 256)];
      }
      W2T[idx] = (short)f2bf(v);
      if (idx < 16) {
        float bb = 0.f;
        if (idx < 8) {
          float s = 0.f;
          for (int j = 0; j < 256; ++j) s += eww[idx * 256 + j] * eb2[j];
          bb = s + ewb[idx] + pb2[idx];
        }
        biasC[idx] = bb;
      }
    }
  } else if (b < o6) {                // wcomb [128][768] + bcomb
    int idx = (b - o5) * 256 + tid;
    if (idx < 128 * 768) {
      int j = idx / 768, k = idx % 768;
      float v = (k < 512) ? wo[j * 512 + k] : cw3[j * 256 + (k - 512)];
      wcomb[idx] = f2bf(v);
      if (idx < 128) bcomb[idx] = bo[idx] + cb3[idx];
    }
  } else if (b < o7) {                // cw2 bf16
    int idx = (b - o6) * 256 + tid;
    if (idx < 256 * 256) cw2bf[idx] = f2bf(cw2[idx]);
  } else if (b < o8) {                // zero d_out coord tail (n*3 f32, /4)
    int idx = (b - o7) * 256 + tid;
    if (idx * 4 < n * 3) {
      float4 z = make_float4(0.f, 0.f, 0.f, 0.f);
      *(float4*)(out_tail + idx * 4) = z;
    }
  } else {                            // count (CSR degree)
    int e = (b - o8) * 256 + tid;
    if (e < E) atomicAdd(&cnt[ei[e]], 1);
  }
}

// ---------- node projections: (469,4), 8-jb loop, nontemporal coalesced stores ----------
__global__ __launch_bounds__(256) void nodeproj_kernel(
    const ushort* __restrict__ h_bf,    // [n][128] bf16
    const ushort* __restrict__ wnode,   // [2048][128]
    const float* __restrict__ bqkv,     // [1536]
    ushort* __restrict__ q_t, uchar* __restrict__ k8, ushort* __restrict__ v_t,
    ushort* __restrict__ P1t, ushort* __restrict__ P2t,
    int n)
{
  __shared__ float oS[64 * 68];         // 17,408 B
  int tid = threadIdx.x;
  int lane = tid & 63, w = tid >> 6;
  int l15 = lane & 15, l4 = lane >> 4;
  int m0 = blockIdx.x * 64;
  int jb0 = blockIdx.y * 8;
  int mrow = m0 + w * 16 + l15;
  int mr = (mrow < n) ? mrow : (n - 1);

  bf16x8 hf[4];
#pragma unroll
  for (int ks = 0; ks < 4; ++ks)
    hf[ks] = *(const bf16x8*)(h_bf + (size_t)mr * 128 + ks * 32 + l4 * 8);

  int row = tid >> 2, cs = (tid & 3) * 16;   // writer mapping
  int gr = m0 + row;

  for (int jb = jb0; jb < jb0 + 8; ++jb) {
    f32x4 acc[4];
#pragma unroll
    for (int nf = 0; nf < 4; ++nf) acc[nf] = (f32x4){0.f, 0.f, 0.f, 0.f};
#pragma unroll
    for (int nf = 0; nf < 4; ++nf)
#pragma unroll
      for (int ks = 0; ks < 4; ++ks) {
        bf16x8 wf = *(const bf16x8*)(wnode + (size_t)(jb * 64 + nf * 16 + l15) * 128 + ks * 32 + l4 * 8);
        acc[nf] = __builtin_amdgcn_mfma_f32_16x16x32_bf16(wf, hf[ks], acc[nf], 0, 0, 0);
      }
    __syncthreads();   // previous jb's readers done
#pragma unroll
    for (int nf = 0; nf < 4; ++nf)
      *(f32x4*)(oS + (w * 16 + l15) * 68 + nf * 16 + l4 * 4) = acc[nf];
    __syncthreads();
    if (gr < n) {
      float4 o0 = *(const float4*)(oS + row * 68 + cs);
      float4 o1 = *(const float4*)(oS + row * 68 + cs + 4);
      float4 o2 = *(const float4*)(oS + row * 68 + cs + 8);
      float4 o3 = *(const float4*)(oS + row * 68 + cs + 12);
      int gc = jb * 64 + cs;
      if (jb < 24) {
        float4 b0 = *(const float4*)(bqkv + gc);
        float4 b1 = *(const float4*)(bqkv + gc + 4);
        float4 b2 = *(const float4*)(bqkv + gc + 8);
        float4 b3 = *(const float4*)(bqkv + gc + 12);
        o0.x += b0.x; o0.y += b0.y; o0.z += b0.z; o0.w += b0.w;
        o1.x += b1.x; o1.y += b1.y; o1.z += b1.z; o1.w += b1.w;
        o2.x += b2.x; o2.y += b2.y; o2.z += b2.z; o2.w += b2.w;
        o3.x += b3.x; o3.y += b3.y; o3.z += b3.z; o3.w += b3.w;
        if (jb < 8) {
          u32x4 s0 = {cvtpk_bf(o0.x,o0.y), cvtpk_bf(o0.z,o0.w), cvtpk_bf(o1.x,o1.y), cvtpk_bf(o1.z,o1.w)};
          u32x4 s1 = {cvtpk_bf(o2.x,o2.y), cvtpk_bf(o2.z,o2.w), cvtpk_bf(o3.x,o3.y), cvtpk_bf(o3.z,o3.w)};
          __builtin_nontemporal_store(s0, (u32x4*)(q_t + (size_t)gr * 512 + gc));
          __builtin_nontemporal_store(s1, (u32x4*)(q_t + (size_t)gr * 512 + gc + 8));
        } else if (jb < 16) {
          u32x4 st = {pk4_e4m3(o0), pk4_e4m3(o1), pk4_e4m3(o2), pk4_e4m3(o3)};
          __builtin_nontemporal_store(st, (u32x4*)(k8 + (size_t)gr * 512 + (gc - 512)));
        } else {
          u32x4 s0 = {cvtpk_bf(o0.x,o0.y), cvtpk_bf(o0.z,o0.w), cvtpk_bf(o1.x,o1.y), cvtpk_bf(o1.z,o1.w)};
          u32x4 s1 = {cvtpk_bf(o2.x,o2.y), cvtpk_bf(o2.z,o2.w), cvtpk_bf(o3.x,o3.y), cvtpk_bf(o3.z,o3.w)};
          __builtin_nontemporal_store(s0, (u32x4*)(v_t + (size_t)gr * 512 + (gc - 1024)));
          __builtin_nontemporal_store(s1, (u32x4*)(v_t + (size_t)gr * 512 + (gc - 1024) + 8));
        }
      } else {
        int pc = (jb & 3) * 64 + cs;
        u32x4 s0 = {cvtpk_bf(o0.x,o0.y), cvtpk_bf(o0.z,o0.w), cvtpk_bf(o1.x,o1.y), cvtpk_bf(o1.z,o1.w)};
        u32x4 s1 = {cvtpk_bf(o2.x,o2.y), cvtpk_bf(o2.z,o2.w), cvtpk_bf(o3.x,o3.y), cvtpk_bf(o3.z,o3.w)};
        ushort* P = (jb < 28) ? P1t : P2t;
        __builtin_nontemporal_store(s0, (u32x4*)(P + (size_t)gr * 256 + pc));
        __builtin_nontemporal_store(s1, (u32x4*)(P + (size_t)gr * 256 + pc + 8));
      }
    }
  }
}

// ---------- CSR scan + fill ----------
__global__ __launch_bounds__(1024) void scan_kernel(int* __restrict__ cnt,
                                                    int* __restrict__ offs, int n) {
  __shared__ int part[1024];
  int t = threadIdx.x;
  int chunk = (n + 1023) >> 10;
  int s = t * chunk, e = min(s + chunk, n);
  int sum = 0;
  for (int i = s; i < e; ++i) sum += cnt[i];
  part[t] = sum;
  __syncthreads();
  for (int off = 1; off < 1024; off <<= 1) {
    int v = (t >= off) ? part[t - off] : 0;
    __syncthreads();
    part[t] += v;
    __syncthreads();
  }
  int run = (t == 0) ? 0 : part[t - 1];
  for (int i = s; i < e; ++i) {
    int c = cnt[i];
    offs[i] = run;
    cnt[i] = run;
    run += c;
  }
  if (t == 1023) offs[n] = run;
}

// pairs[slot] = (col, row | (masked ? 0x80000000 : 0))
__global__ __launch_bounds__(256) void fill_kernel(const int* __restrict__ ei,
                                                   const int* __restrict__ mask,
                                                   int* __restrict__ cursor,
                                                   int2* __restrict__ pairs, int E) {
  int e = blockIdx.x * 256 + threadIdx.x;
  if (e < E) {
    int r = ei[e];
    int p = atomicAdd(&cursor[r], 1);
    int rm = r | (mask[e] ? 0 : (int)0x80000000u);
    pairs[p] = make_int2(ei[E + e], rm);
  }
}

// ---------- edge MLP v3: factorized, CSR-ordered ----------
#define EB 64
#define GS 40       // geom stride (shorts)
#define TS 72       // t1 stride (shorts)

__global__ __launch_bounds__(256) void edge_mfma3_kernel(
    const float* __restrict__ x,
    const int2* __restrict__ pairs, int E,
    const short* __restrict__ W1g,      // [512][32]
    const short* __restrict__ W2T, const float* __restrict__ biasC,
    const ushort* __restrict__ P1t, const ushort* __restrict__ P2t,
    float* __restrict__ scores)
{
  __shared__ short geomL[EB * GS];      // 5 KB
  __shared__ int2 rcL[EB];              // 0.5 KB
  __shared__ short T1[4 * EB * TS];     // 36,864 B
  float* slab = (float*)T1;             // overlay after layer2

  int tid = threadIdx.x;
  int lane = tid & 63, w = tid >> 6;
  int l15 = lane & 15, l4 = lane >> 4;
  int eb0 = blockIdx.x * EB;

  if (tid < EB) {
    int i = min(eb0 + tid, E - 1);
    int2 pr = pairs[i];
    rcL[tid] = pr;
    int c = pr.x, r = pr.y & 0x7fffffff;
    float xr0 = x[r*3], xr1 = x[r*3+1], xr2 = x[r*3+2];
    float xc0 = x[c*3], xc1 = x[c*3+1], xc2 = x[c*3+2];
    float d0 = xr0-xc0, d1 = xr1-xc1, d2 = xr2-xc2;
    bf16x8 g;
    g[0] = (short)0x3F80;               // 1.0 (bias input)
    g[1] = (short)f2bf(d0*d0 + d1*d1 + d2*d2);
    g[2] = (short)f2bf(xr0); g[3] = (short)f2bf(xr1); g[4] = (short)f2bf(xr2);
    g[5] = (short)f2bf(xc0); g[6] = (short)f2bf(xc1); g[7] = (short)f2bf(xc2);
    bf16x8 z = {0,0,0,0,0,0,0,0};
    *(bf16x8*)(geomL + tid * GS) = g;
    *(bf16x8*)(geomL + tid * GS + 8) = z;
    *(bf16x8*)(geomL + tid * GS + 16) = z;
    *(bf16x8*)(geomL + tid * GS + 24) = z;
    *(bf16x8*)(geomL + tid * GS + 32) = z;
  }
  __syncthreads();

  int rr[4], cc[4];
  bf16x8 bE[4];
#pragma unroll
  for (int ef = 0; ef < 4; ++ef) {
    int2 pr = rcL[ef * 16 + l15];
    cc[ef] = pr.x; rr[ef] = pr.y & 0x7fffffff;
    bE[ef] = *(const bf16x8*)(geomL + (ef * 16 + l15) * GS + l4 * 8);
  }

  f32x4 sacc[4];
#pragma unroll
  for (int ef = 0; ef < 4; ++ef) sacc[ef] = (f32x4){0.f, 0.f, 0.f, 0.f};

  short* t1w = T1 + w * (EB * TS);

#pragma unroll
  for (int cch = 0; cch < 2; ++cch) {
    const int n0 = cch ? (256 + w * 64) : (w * 64);
    f32x4 acc[4][4];
#pragma unroll
    for (int mf = 0; mf < 4; ++mf) {
      bf16x8 aW = *(const bf16x8*)(W1g + (size_t)(n0 + mf * 16 + l15) * 32 + l4 * 8);
#pragma unroll
      for (int ef = 0; ef < 4; ++ef)
        acc[mf][ef] = __builtin_amdgcn_mfma_f32_16x16x32_bf16(
            aW, bE[ef], (f32x4){0.f, 0.f, 0.f, 0.f}, 0, 0, 0);
    }
    if (cch == 0) {
#pragma unroll
      for (int mf = 0; mf < 4; ++mf) {
        int colb = n0 + mf * 16 + l4 * 4;
        uint2 g1[4], g2[4];
#pragma unroll
        for (int ef = 0; ef < 4; ++ef) {
          g1[ef] = *(const uint2*)(P1t + (size_t)rr[ef] * 256 + colb);
          g2[ef] = *(const uint2*)(P2t + (size_t)cc[ef] * 256 + colb);
        }
#pragma unroll
        for (int ef = 0; ef < 4; ++ef) {
          f32x4 a = acc[mf][ef];
          a[0] += bf2f_lo(g1[ef].x) + bf2f_lo(g2[ef].x);
          a[1] += bf2f_hi(g1[ef].x) + bf2f_hi(g2[ef].x);
          a[2] += bf2f_lo(g1[ef].y) + bf2f_lo(g2[ef].y);
          a[3] += bf2f_hi(g1[ef].y) + bf2f_hi(g2[ef].y);
          acc[mf][ef] = a;
        }
      }
    }
#pragma unroll
    for (int mf = 0; mf < 4; ++mf) {
      int nl = mf * 16 + l4 * 4;
#pragma unroll
      for (int ef = 0; ef < 4; ++ef) {
        int e = ef * 16 + l15;
        f32x4 v = acc[mf][ef];
        float s0 = silu_fast(v[0]);
        float s1 = silu_fast(v[1]);
        float s2 = silu_fast(v[2]);
        float s3 = silu_fast(v[3]);
        uint2 pk;
        pk.x = cvtpk_bf(s0, s1);
        pk.y = cvtpk_bf(s2, s3);
        *(uint2*)(t1w + e * TS + nl) = pk;
      }
    }
#pragma unroll
    for (int ks2 = 0; ks2 < 2; ++ks2) {
      bf16x8 bW2 = *(const bf16x8*)(W2T + (size_t)l15 * 512 + n0 + ks2 * 32 + l4 * 8);
#pragma unroll
      for (int ef = 0; ef < 4; ++ef) {
        bf16x8 aT = *(const bf16x8*)(t1w + (ef * 16 + l15) * TS + ks2 * 32 + l4 * 8);
        sacc[ef] = __builtin_amdgcn_mfma_f32_16x16x32_bf16(aT, bW2, sacc[ef], 0, 0, 0);
      }
    }
  }
  __syncthreads();
#pragma unroll
  for (int ef = 0; ef < 4; ++ef)
#pragma unroll
    for (int i = 0; i < 4; ++i)
      slab[(w * EB + ef * 16 + l4 * 4 + i) * 16 + l15] = sacc[ef][i];
  __syncthreads();
  for (int t = tid; t < EB * 8; t += 256) {
    int e = t >> 3, hh = t & 7;
    float s = biasC[hh]
            + slab[(0 * EB + e) * 16 + hh] + slab[(1 * EB + e) * 16 + hh]
            + slab[(2 * EB + e) * 16 + hh] + slab[(3 * EB + e) * 16 + hh];
    if (rcL[e].y < 0) s = -1e9f;
    if (eb0 + e < E) scores[(size_t)(eb0 + e) * 8 + hh] = s;
  }
}

// ---------- fused QK + softmax + aggregation (no-max softmax, 2-wide pipeline) ----------
__global__ __launch_bounds__(256) void attn_fused_kernel(
    const int* __restrict__ offs,
    const int2* __restrict__ pairs,
    const float* __restrict__ scores,
    const ushort* __restrict__ q_t,
    const uchar* __restrict__ k8,
    const ushort* __restrict__ v_t,
    ushort* __restrict__ agg, int n)
{
  int node = blockIdx.x * 4 + (threadIdx.x >> 6);
  if (node >= n) return;
  int lane = threadIdx.x & 63;
  int hh = lane >> 3;
  int start = offs[node], end = offs[node + 1];

  bf16x8 qv = *(const bf16x8*)(q_t + (size_t)node * 512 + lane * 8);
  float qf[8];
#pragma unroll
  for (int j = 0; j < 8; ++j) qf[j] = bf2f((ushort)qv[j]) * 0x1p+120f;

  float ssum = 0.f;
  float acc[8];
#pragma unroll
  for (int j = 0; j < 8; ++j) acc[j] = 0.f;

  if (start < end) {
    int ib = min(start + 1, end - 1);
    int c0 = pairs[start].x, c1 = pairs[ib].x;
    uint2 kwa = *(const uint2*)(k8 + (size_t)c0 * 512 + lane * 8);
    bf16x8 vva = *(const bf16x8*)(v_t + (size_t)c0 * 512 + lane * 8);
    float sma = scores[(size_t)start * 8 + hh];
    uint2 kwb = *(const uint2*)(k8 + (size_t)c1 * 512 + lane * 8);
    bf16x8 vvb = *(const bf16x8*)(v_t + (size_t)c1 * 512 + lane * 8);
    float smb = scores[(size_t)ib * 8 + hh];

    for (int i = start; i < end; i += 2) {
      uint2 k0 = kwa, k1 = kwb;
      bf16x8 v0 = vva, v1 = vvb;
      float s0 = sma, s1 = smb;
      bool has1 = (i + 1) < end;
      // prefetch next pair
      int j0 = min(i + 2, end - 1), j1 = min(i + 3, end - 1);
      int d0 = pairs[j0].x, d1 = pairs[j1].x;
      kwa = *(const uint2*)(k8 + (size_t)d0 * 512 + lane * 8);
      vva = *(const bf16x8*)(v_t + (size_t)d0 * 512 + lane * 8);
      sma = scores[(size_t)j0 * 8 + hh];
      kwb = *(const uint2*)(k8 + (size_t)d1 * 512 + lane * 8);
      vvb = *(const bf16x8*)(v_t + (size_t)d1 * 512 + lane * 8);
      smb = scores[(size_t)j1 * 8 + hh];

      float dot0 = 0.f, dot1 = 0.f;
#pragma unroll
      for (int j = 0; j < 4; ++j) {
        dot0 = fmaf(qf[j],     e4m3_raw((k0.x >> (8 * j)) & 0xffu), dot0);
        dot0 = fmaf(qf[4 + j], e4m3_raw((k0.y >> (8 * j)) & 0xffu), dot0);
        dot1 = fmaf(qf[j],     e4m3_raw((k1.x >> (8 * j)) & 0xffu), dot1);
        dot1 = fmaf(qf[4 + j], e4m3_raw((k1.y >> (8 * j)) & 0xffu), dot1);
      }
      dot0 += __shfl_xor(dot0, 1); dot0 += __shfl_xor(dot0, 2); dot0 += __shfl_xor(dot0, 4);
      dot1 += __shfl_xor(dot1, 1); dot1 += __shfl_xor(dot1, 2); dot1 += __shfl_xor(dot1, 4);
      float sc0 = (s0 < -5e8f) ? -1e9f : fmaf(dot0, 0.125f, s0);
      float sc1 = (!has1 || s1 < -5e8f) ? -1e9f : fmaf(dot1, 0.125f, s1);
      float e0 = __expf(sc0);
      float e1 = __expf(sc1);
      ssum += e0 + e1;
#pragma unroll
      for (int j = 0; j < 8; ++j) {
        acc[j] = fmaf(e0, bf2f((ushort)v0[j]), acc[j]);
        acc[j] = fmaf(e1, bf2f((ushort)v1[j]), acc[j]);
      }
    }
  }
  float inv = __builtin_amdgcn_rcpf(ssum + 1e-8f);
  ushort8 ov;
#pragma unroll
  for (int j = 0; j < 8; ++j) ov[j] = f2bf(acc[j] * inv);
  *(ushort8*)(agg + (size_t)node * 512 + lane * 8) = ov;
}

// ---------- coord layer 2 via MFMA: c2 = silu(c1 @ cw2^T + cb2) bf16 ----------
__global__ __launch_bounds__(256) void c2_mfma_kernel(const ushort* __restrict__ c1,
                                                      const ushort* __restrict__ cw2bf,
                                                      const float* __restrict__ cb2,
                                                      ushort* __restrict__ c2, int n) {
  __shared__ float oS[64 * 68];
  int tid = threadIdx.x;
  int lane = tid & 63, w = tid >> 6;
  int l15 = lane & 15, l4 = lane >> 4;
  int m0 = blockIdx.x * 64;
  int n0 = blockIdx.y * 64 + w * 16;

  f32x4 acc[4];
#pragma unroll
  for (int mf = 0; mf < 4; ++mf) acc[mf] = (f32x4){0.f, 0.f, 0.f, 0.f};
#pragma unroll
  for (int ks = 0; ks < 8; ++ks) {
    bf16x8 bW = *(const bf16x8*)(cw2bf + (size_t)(n0 + l15) * 256 + ks * 32 + l4 * 8);
#pragma unroll
    for (int mf = 0; mf < 4; ++mf) {
      int gr = m0 + mf * 16 + l15; if (gr >= n) gr = n - 1;
      bf16x8 aH = *(const bf16x8*)(c1 + (size_t)gr * 256 + ks * 32 + l4 * 8);
      acc[mf] = __builtin_amdgcn_mfma_f32_16x16x32_bf16(aH, bW, acc[mf], 0, 0, 0);
    }
  }
#pragma unroll
  for (int mf = 0; mf < 4; ++mf)
#pragma unroll
    for (int i = 0; i < 4; ++i)
      oS[(mf * 16 + l4 * 4 + i) * 68 + w * 16 + l15] = acc[mf][i];
  __syncthreads();
  {
    int row = tid >> 2, cs = (tid & 3) * 16;
    int gr = m0 + row;
    if (gr < n) {
      int gc = blockIdx.y * 64 + cs;
      ushort8 o0, o1;
#pragma unroll
      for (int j = 0; j < 8; ++j) o0[j] = f2bf(silu_fast(oS[row * 68 + cs + j] + cb2[gc + j]));
#pragma unroll
      for (int j = 0; j < 8; ++j) o1[j] = f2bf(silu_fast(oS[row * 68 + cs + 8 + j] + cb2[gc + 8 + j]));
      *(ushort8*)(c2 + (size_t)gr * 256 + gc) = o0;
      *(ushort8*)(c2 + (size_t)gr * 256 + gc + 8) = o1;
    }
  }
}

// ---------- final fused out GEMM: out[n][128] = [agg|c2] @ wcomb^T + bcomb ----------
__global__ __launch_bounds__(256) void final_mfma_kernel(const ushort* __restrict__ agg,
                                                         const ushort* __restrict__ c2,
                                                         const ushort* __restrict__ wcomb,
                                                         const float* __restrict__ bcomb,
                                                         float* __restrict__ out, int n) {
  __shared__ float oS[64 * 68];
  int tid = threadIdx.x;
  int lane = tid & 63, w = tid >> 6;
  int l15 = lane & 15, l4 = lane >> 4;
  int m0 = blockIdx.x * 64;
  int jb = blockIdx.y;
  int n0 = jb * 64 + w * 16;

  f32x4 acc[4];
#pragma unroll
  for (int mf = 0; mf < 4; ++mf) acc[mf] = (f32x4){0.f, 0.f, 0.f, 0.f};
#pragma unroll
  for (int ks = 0; ks < 24; ++ks) {
    bf16x8 bW = *(const bf16x8*)(wcomb + (size_t)(n0 + l15) * 768 + ks * 32 + l4 * 8);
#pragma unroll
    for (int mf = 0; mf < 4; ++mf) {
      int gr = m0 + mf * 16 + l15; if (gr >= n) gr = n - 1;
      const ushort* ap = (ks < 16) ? (agg + (size_t)gr * 512 + ks * 32)
                                   : (c2 + (size_t)gr * 256 + (ks - 16) * 32);
      bf16x8 aH = *(const bf16x8*)(ap + l4 * 8);
      acc[mf] = __builtin_amdgcn_mfma_f32_16x16x32_bf16(aH, bW, acc[mf], 0, 0, 0);
    }
  }
#pragma unroll
  for (int mf = 0; mf < 4; ++mf)
#pragma unroll
    for (int i = 0; i < 4; ++i)
      oS[(mf * 16 + l4 * 4 + i) * 68 + w * 16 + l15] = acc[mf][i];
  __syncthreads();
  {
    int row = tid >> 2, cs = (tid & 3) * 16;
    int gr = m0 + row;
    if (gr < n) {
      int gc = jb * 64 + cs;
#pragma unroll
      for (int g = 0; g < 4; ++g) {
        float4 o;
        o.x = oS[row * 68 + cs + g * 4 + 0] + bcomb[gc + g * 4 + 0];
        o.y = oS[row * 68 + cs + g * 4 + 1] + bcomb[gc + g * 4 + 1];
        o.z = oS[row * 68 + cs + g * 4 + 2] + bcomb[gc + g * 4 + 2];
        o.w = oS[row * 68 + cs + g * 4 + 3] + bcomb[gc + g * 4 + 3];
        *(float4*)(out + (size_t)gr * 128 + gc + g * 4) = o;
      }
    }
  }
}

// ---------- launch ----------
extern "C" void kernel_launch(void* const* d_in, const int* in_sizes, int n_in,
                              void* d_out, int out_size, void* d_ws, size_t ws_size,
                              hipStream_t stream) {
  const float* h   = (const float*)d_in[0];
  const float* x   = (const float*)d_in[1];
  const int*   ei  = (const int*)d_in[2];
  const int*   mask= (const int*)d_in[3];
  const float* wq  = (const float*)d_in[4];
  const float* bq  = (const float*)d_in[5];
  const float* wk  = (const float*)d_in[6];
  const float* bk  = (const float*)d_in[7];
  const float* wv  = (const float*)d_in[8];
  const float* bv  = (const float*)d_in[9];
  const float* wo  = (const float*)d_in[10];
  const float* bo  = (const float*)d_in[11];
  const float* pw1 = (const float*)d_in[12];
  const float* pb1 = (const float*)d_in[13];
  const float* pw2 = (const float*)d_in[14];
  const float* pb2 = (const float*)d_in[15];
  const float* ew1 = (const float*)d_in[16];
  const float* eb1 = (const float*)d_in[17];
  const float* ew2 = (const float*)d_in[18];
  const float* eb2 = (const float*)d_in[19];
  const float* eww = (const float*)d_in[20];
  const float* ewb = (const float*)d_in[21];
  const float* cw1 = (const float*)d_in[22];
  const float* cb1 = (const float*)d_in[23];
  const float* cw2 = (const float*)d_in[24];
  const float* cb2 = (const float*)d_in[25];
  const float* cw3 = (const float*)d_in[26];
  const float* cb3 = (const float*)d_in[27];

  int n = in_sizes[0] / 128;
  int E = in_sizes[3];

  char* wptr = (char*)d_ws;
  auto alloc = [&](size_t bytes) {
    char* p = wptr;
    wptr += (bytes + 255) & ~(size_t)255;
    return p;
  };
  ushort* q_t   = (ushort*)alloc((size_t)n * 512 * 2);   // also reused as agg
  uchar*  k8    = (uchar*)alloc((size_t)n * 512);
  ushort* v_t   = (ushort*)alloc((size_t)n * 512 * 2);
  ushort* P1t   = (ushort*)alloc((size_t)n * 256 * 2);
  ushort* P2t   = (ushort*)alloc((size_t)n * 256 * 2);
  ushort* h_bf  = (ushort*)alloc((size_t)n * 128 * 2);
  float* scores = (float*)alloc((size_t)E * 8 * 4);
  ushort* c1    = (ushort*)alloc((size_t)n * 256 * 2);
  ushort* c2    = (ushort*)alloc((size_t)n * 256 * 2);
  ushort* wnode = (ushort*)alloc((size_t)2048 * 128 * 2);
  float* bqkv   = (float*)alloc((size_t)1536 * 4);
  short* W1g    = (short*)alloc((size_t)512 * 32 * 2);
  short* W2T    = (short*)alloc((size_t)16 * 512 * 2);
  float* biasC  = (float*)alloc((size_t)16 * 4);
  ushort* wcomb = (ushort*)alloc((size_t)128 * 768 * 2);
  float* bcomb  = (float*)alloc((size_t)128 * 4);
  ushort* cw2bf = (ushort*)alloc((size_t)256 * 256 * 2);
  int* offs     = (int*)alloc((size_t)(n + 1) * 4);
  int* cursor   = (int*)alloc((size_t)n * 4);
  int2* pairs   = (int2*)alloc((size_t)E * 8);
  ushort* agg   = q_t;    // overlay: attn reads q[node] before writing agg[node]

  hipMemsetAsync(cursor, 0, (size_t)n * 4, stream);

  // mega-prep segment boundaries
  int b_h2  = (n * 128 / 4 + 255) / 256;
  int b_c1  = (n * 64 + 255) / 256;
  int b_wn  = (2048 * 128) / 256;
  int b_w1  = (512 * 32 + 255) / 256;
  int b_w2  = (16 * 512 + 255) / 256;
  int b_wc  = (128 * 768 + 255) / 256;
  int b_cw  = (256 * 256 + 255) / 256;
  int b_zo  = ((n * 3) / 4 + 255) / 256;
  int b_cnt = (E + 255) / 256;
  int o1 = b_h2, o2 = o1 + b_c1, o3 = o2 + b_wn, o4 = o3 + b_w1;
  int o5 = o4 + b_w2, o6 = o5 + b_wc, o7 = o6 + b_cw, o8 = o7 + b_zo;
  int total_blocks = o8 + b_cnt;

  mega_prep<<<dim3(total_blocks), 256, 0, stream>>>(
      h, x, ei, wq, wk, wv, bq, bk, bv, ew1, eb1, pw1, pb1, ew2, eww, eb2, ewb,
      pw2, pb2, wo, cw3, bo, cb3, cw1, cb1, cw2,
      h_bf, c1, wnode, bqkv, W1g, W2T, biasC, wcomb, bcomb, cw2bf,
      (float*)d_out + (size_t)n * 128, cursor,
      n, E, o1, o2, o3, o4, o5, o6, o7, o8);

  scan_kernel<<<dim3(1), 1024, 0, stream>>>(cursor, offs, n);
  fill_kernel<<<dim3((E + 255) / 256), 256, 0, stream>>>(ei, mask, cursor, pairs, E);

  nodeproj_kernel<<<dim3((n + 63) / 64, 4), 256, 0, stream>>>(
      h_bf, wnode, bqkv, q_t, k8, v_t, P1t, P2t, n);

  edge_mfma3_kernel<<<dim3((E + EB - 1) / EB), 256, 0, stream>>>(
      x, pairs, E, W1g, W2T, biasC, P1t, P2t, scores);

  attn_fused_kernel<<<dim3((n + 3) / 4), 256, 0, stream>>>(
      offs, pairs, scores, q_t, k8, v_t, agg, n);

  c2_mfma_kernel<<<dim3((n + 63) / 64, 4), 256, 0, stream>>>(c1, cw2bf, cb2, c2, n);

  final_mfma_kernel<<<dim3((n + 63) / 64, 2), 256, 0, stream>>>(agg, c2, wcomb, bcomb,
                                                                (float*)d_out, n);
}